// Round 3
// baseline (1415.448 us; speedup 1.0000x reference)
//
#include <hip/hip_runtime.h>
#include <hip/hip_bf16.h>

#define NN 50000
#define EE 800000
#define ETOT 850000   // EE + NN self-loops
#define FIN 500
#define HC 128        // 8 heads * 16 ch
#define NH 8
#define CH 16
#define NC 7

// canonical fp32 weight-buffer offsets
#define OW1  0
#define OAS1 64000
#define OAD1 64128
#define OB1  64256
#define OW2  64384
#define OAS2 65280
#define OAD2 65287
#define OB2  65294
#define WTOT 65301

typedef __hip_bfloat16 bf16;

__device__ __forceinline__ float b2f(const bf16 v) { return __bfloat162float(v); }
__device__ __forceinline__ float lrelu(float v) { return fmaxf(v, 0.2f * v); }
__device__ __forceinline__ float elog(float v) { return __expf(fminf(lrelu(v), 30.f)); }

__device__ __forceinline__ bool edge_sd(const int* __restrict__ esrc,
                                        const int* __restrict__ edst,
                                        int e, int& s, int& d)
{
    if (e < EE) { s = esrc[e]; d = edst[e]; }
    else        { s = d = e - EE; }
    return ((unsigned)s < (unsigned)NN) && ((unsigned)d < (unsigned)NN);
}

// ---------------- dtype detection ----------------
// flags[0]=1 if x is bf16, 0 if fp32.  flags[1]=1 if edge_index is int64, 0 if int32.
__global__ void detect_kernel(const unsigned short* __restrict__ xraw,
                              const unsigned int* __restrict__ eraw,
                              int* __restrict__ flags)
{
    __shared__ int s_insane, s_oddnz;
    if (threadIdx.x == 0) { s_insane = 0; s_oddnz = 0; }
    __syncthreads();
    int insane = 0;
    for (int i = threadIdx.x; i < 8192; i += 256) {
        const unsigned int bits = ((unsigned int)xraw[i]) << 16;
        const float v = __uint_as_float(bits);
        const float a = fabsf(v);
        const bool sane = (v == 0.0f) || (a >= 1e-30f && a <= 1e4f);  // NaN -> not sane
        if (!sane) insane++;
    }
    int oddnz = 0;
    for (int i = threadIdx.x; i < 512; i += 256) {
        if (eraw[2 * i + 1] != 0u) oddnz++;
    }
    atomicAdd(&s_insane, insane);
    atomicAdd(&s_oddnz, oddnz);
    __syncthreads();
    if (threadIdx.x == 0) {
        flags[0] = (s_insane < 256) ? 1 : 0;
        flags[1] = (s_oddnz == 0) ? 1 : 0;
    }
}

// ---------------- canonicalize edge_index to int32 ----------------
__global__ void conv_edge_kernel(const void* __restrict__ eidx, int* __restrict__ e32,
                                 const int* __restrict__ flags)
{
    const int i = blockIdx.x * blockDim.x + threadIdx.x;
    if (i >= 2 * EE) return;
    int v;
    if (flags[1]) v = (int)((const long long*)eidx)[i];   // branch is real: no OOB speculation
    else          v = ((const int*)eidx)[i];
    e32[i] = v;
}

// ---------------- canonicalize all small weights to fp32 ----------------
__global__ void conv_w_kernel(const void* W1, const void* as1, const void* ad1, const void* b1,
                              const void* W2, const void* as2, const void* ad2, const void* b2,
                              float* __restrict__ wc, const int* __restrict__ flags)
{
    const int i = blockIdx.x * blockDim.x + threadIdx.x;
    if (i >= WTOT) return;
    const void* src; int off;
    if (i < OAS1)      { src = W1;  off = i - OW1; }
    else if (i < OAD1) { src = as1; off = i - OAS1; }
    else if (i < OB1)  { src = ad1; off = i - OAD1; }
    else if (i < OW2)  { src = b1;  off = i - OB1; }
    else if (i < OAS2) { src = W2;  off = i - OW2; }
    else if (i < OAD2) { src = as2; off = i - OAS2; }
    else if (i < OB2)  { src = ad2; off = i - OAD2; }
    else               { src = b2;  off = i - OB2; }
    float v;
    if (flags[0]) v = b2f(((const bf16*)src)[off]);
    else          v = ((const float*)src)[off];
    wc[i] = v;
}

// ---------------- GEMM1: h1[N,128](bf16) = x[N,500] @ W1[500,128] ----------------
__global__ __launch_bounds__(256) void gemm1_kernel(
    const void* __restrict__ x, const float* __restrict__ wc,
    bf16* __restrict__ h1, const int* __restrict__ flags)
{
    __shared__ float As[32][128];   // k-major: As[k][row]
    __shared__ float Bs[32][128];   // k-major: Bs[k][col]
    const int isbf = flags[0];
    const bf16*  xb = (const bf16*)x;
    const float* xf = (const float*)x;
    const int t  = threadIdx.x;
    const int tx = t & 15;
    const int ty = t >> 4;
    const int r0 = blockIdx.x * 128;

    float acc[8][8];
#pragma unroll
    for (int i = 0; i < 8; ++i)
#pragma unroll
        for (int j = 0; j < 8; ++j) acc[i][j] = 0.f;

    const int arow = t >> 1;
    const int aka  = (t & 1) * 16;
    const int bcol = t & 127;
    const int bkb  = (t >> 7) * 16;

    for (int k0 = 0; k0 < FIN; k0 += 32) {
        {
            const int grow = r0 + arow;
            const bool rowok = (grow < NN);
            const size_t base = (size_t)grow * FIN;
            if (isbf) {
#pragma unroll
                for (int j = 0; j < 16; ++j) {
                    const int k = k0 + aka + j;
                    float v = 0.f;
                    if (rowok && k < FIN) v = b2f(xb[base + k]);
                    As[aka + j][arow] = v;
                }
            } else {
#pragma unroll
                for (int j = 0; j < 16; ++j) {
                    const int k = k0 + aka + j;
                    float v = 0.f;
                    if (rowok && k < FIN) v = xf[base + k];
                    As[aka + j][arow] = v;
                }
            }
        }
#pragma unroll
        for (int j = 0; j < 16; ++j) {
            const int k = k0 + bkb + j;
            Bs[bkb + j][bcol] = (k < FIN) ? wc[OW1 + k * HC + bcol] : 0.f;
        }
        __syncthreads();
#pragma unroll
        for (int kk = 0; kk < 32; ++kk) {
            const float4 a0 = *(const float4*)&As[kk][8 * ty];
            const float4 a1 = *(const float4*)&As[kk][8 * ty + 4];
            const float4 b0 = *(const float4*)&Bs[kk][4 * tx];
            const float4 b1 = *(const float4*)&Bs[kk][64 + 4 * tx];
            const float av[8] = {a0.x, a0.y, a0.z, a0.w, a1.x, a1.y, a1.z, a1.w};
            const float bv[8] = {b0.x, b0.y, b0.z, b0.w, b1.x, b1.y, b1.z, b1.w};
#pragma unroll
            for (int i = 0; i < 8; ++i)
#pragma unroll
                for (int j = 0; j < 8; ++j) acc[i][j] += av[i] * bv[j];
        }
        __syncthreads();
    }
#pragma unroll
    for (int i = 0; i < 8; ++i) {
        const int row = r0 + 8 * ty + i;
        if (row < NN) {
            bf16* hp = h1 + (size_t)row * HC;
#pragma unroll
            for (int j = 0; j < 4; ++j) {
                hp[4 * tx + j]      = __float2bfloat16(acc[i][j]);
                hp[64 + 4 * tx + j] = __float2bfloat16(acc[i][4 + j]);
            }
        }
    }
}

// ---------------- per-node attention logits, layer 1 ----------------
__global__ void att1_kernel(const bf16* __restrict__ h1, const float* __restrict__ wc,
                            float* __restrict__ a_src, float* __restrict__ a_dst)
{
    const int idx = blockIdx.x * blockDim.x + threadIdx.x;   // n*8 + h
    if (idx >= NN * NH) return;
    const int h = idx & 7;
    const bf16* hp = h1 + (size_t)(idx >> 3) * HC + h * CH;
    float s = 0.f, d = 0.f;
#pragma unroll
    for (int c = 0; c < CH; ++c) {
        const float hv = b2f(hp[c]);
        s += hv * wc[OAS1 + h * CH + c];
        d += hv * wc[OAD1 + h * CH + c];
    }
    a_src[idx] = s;
    a_dst[idx] = d;
}

// ---------------- layer-1 softmax denominator ----------------
__global__ void edge1_denom_kernel(const int* __restrict__ esrc, const int* __restrict__ edst,
                                   const float* __restrict__ a_src, const float* __restrict__ a_dst,
                                   float* __restrict__ denom)
{
    const int e = blockIdx.x * blockDim.x + threadIdx.x;
    if (e >= ETOT) return;
    int s, d;
    if (!edge_sd(esrc, edst, e, s, d)) return;
    const float4 as0 = *(const float4*)&a_src[s * NH];
    const float4 as1 = *(const float4*)&a_src[s * NH + 4];
    const float4 ad0 = *(const float4*)&a_dst[d * NH];
    const float4 ad1 = *(const float4*)&a_dst[d * NH + 4];
    float ex[8];
    ex[0] = elog(as0.x + ad0.x);
    ex[1] = elog(as0.y + ad0.y);
    ex[2] = elog(as0.z + ad0.z);
    ex[3] = elog(as0.w + ad0.w);
    ex[4] = elog(as1.x + ad1.x);
    ex[5] = elog(as1.y + ad1.y);
    ex[6] = elog(as1.z + ad1.z);
    ex[7] = elog(as1.w + ad1.w);
    float* dn = denom + (size_t)d * NH;
#pragma unroll
    for (int h = 0; h < NH; ++h) atomicAdd(dn + h, ex[h]);
}

// ---------------- layer-1 aggregation, FULL (fast path) ----------------
__global__ __launch_bounds__(256) void edge1_aggr_full_kernel(
    const int* __restrict__ esrc, const int* __restrict__ edst,
    const float* __restrict__ a_src, const float* __restrict__ a_dst,
    const float* __restrict__ denom, const bf16* __restrict__ h1, float* __restrict__ out1)
{
    const int e = blockIdx.x * 2 + (threadIdx.x >> 7);
    if (e >= ETOT) return;
    const int c = threadIdx.x & 127;
    int s, d;
    if (!edge_sd(esrc, edst, e, s, d)) return;
    const int h = c >> 4;
    const float num   = elog(a_src[s * NH + h] + a_dst[d * NH + h]);
    const float alpha = num / (denom[d * NH + h] + 1e-16f);
    atomicAdd(&out1[(size_t)d * HC + c], b2f(h1[(size_t)s * HC + c]) * alpha);
}

// ---------------- layer-1 aggregation, ONE HEAD (slow path) ----------------
__global__ __launch_bounds__(256) void edge1_aggr_head_kernel(
    const int* __restrict__ esrc, const int* __restrict__ edst,
    const float* __restrict__ a_src, const float* __restrict__ a_dst,
    const float* __restrict__ denom, const bf16* __restrict__ h1,
    float* __restrict__ out1h, int head)
{
    const int idx = blockIdx.x * blockDim.x + threadIdx.x;
    if (idx >= ETOT * 16) return;
    const int e = idx >> 4;
    const int c = idx & 15;
    int s, d;
    if (!edge_sd(esrc, edst, e, s, d)) return;
    const float num   = elog(a_src[s * NH + head] + a_dst[d * NH + head]);
    const float alpha = num / (denom[d * NH + head] + 1e-16f);
    atomicAdd(&out1h[(size_t)d * CH + c],
              b2f(h1[(size_t)s * HC + head * CH + c]) * alpha);
}

// ---------------- fast path: bias+relu in place ----------------
__global__ void bias_relu_kernel(float* __restrict__ out1, const float* __restrict__ wc)
{
    const int idx = blockIdx.x * blockDim.x + threadIdx.x;
    if (idx >= NN * HC) return;
    out1[idx] = fmaxf(out1[idx] + wc[OB1 + (idx & 127)], 0.f);
}

// ---------------- fast path GEMM2 ----------------
__global__ __launch_bounds__(256) void gemm2_kernel(
    const float* __restrict__ hrelu, const float* __restrict__ wc, float* __restrict__ h2)
{
    __shared__ float W2s[HC * NC];
    for (int i = threadIdx.x; i < HC * NC; i += 256) W2s[i] = wc[OW2 + i];
    __syncthreads();
    const int nl = threadIdx.x >> 3;
    const int c  = threadIdx.x & 7;
    const int node = blockIdx.x * 32 + nl;
    if (c >= NC || node >= NN) return;
    const float* hp = hrelu + (size_t)node * HC;
    float acc = 0.f;
#pragma unroll
    for (int k4 = 0; k4 < 32; ++k4) {
        const float4 hv = *(const float4*)&hp[4 * k4];
        acc += hv.x * W2s[(4 * k4 + 0) * NC + c];
        acc += hv.y * W2s[(4 * k4 + 1) * NC + c];
        acc += hv.z * W2s[(4 * k4 + 2) * NC + c];
        acc += hv.w * W2s[(4 * k4 + 3) * NC + c];
    }
    h2[node * NC + c] = acc;
}

// ---------------- slow path: per-head bias+relu+GEMM2 partial ----------------
__global__ __launch_bounds__(256) void gemm2_head_kernel(
    const float* __restrict__ out1h, const float* __restrict__ wc,
    float* __restrict__ h2, int head)
{
    const int idx = blockIdx.x * blockDim.x + threadIdx.x;   // n*8 + c
    const int n = idx >> 3;
    const int c = idx & 7;
    if (n >= NN || c >= NC) return;
    const float* op = out1h + (size_t)n * CH;
    float acc = 0.f;
#pragma unroll
    for (int k = 0; k < CH; ++k) {
        const float v = fmaxf(op[k] + wc[OB1 + head * CH + k], 0.f);
        acc += v * wc[OW2 + (head * CH + k) * NC + c];
    }
    h2[n * NC + c] += acc;
}

// ---------------- per-node attention logits, layer 2 ----------------
__global__ void att2_kernel(const float* __restrict__ h2, const float* __restrict__ wc,
                            float* __restrict__ a_src, float* __restrict__ a_dst)
{
    const int n = blockIdx.x * blockDim.x + threadIdx.x;
    if (n >= NN) return;
    float s = 0.f, d = 0.f;
#pragma unroll
    for (int c = 0; c < NC; ++c) {
        const float hv = h2[n * NC + c];
        s += hv * wc[OAS2 + c];
        d += hv * wc[OAD2 + c];
    }
    a_src[n] = s;
    a_dst[n] = d;
}

__global__ void edge2_denom_kernel(const int* __restrict__ esrc, const int* __restrict__ edst,
                                   const float* __restrict__ a_src, const float* __restrict__ a_dst,
                                   float* __restrict__ denom)
{
    const int e = blockIdx.x * blockDim.x + threadIdx.x;
    if (e >= ETOT) return;
    int s, d;
    if (!edge_sd(esrc, edst, e, s, d)) return;
    atomicAdd(&denom[d], elog(a_src[s] + a_dst[d]));
}

__global__ void edge2_aggr_kernel(const int* __restrict__ esrc, const int* __restrict__ edst,
                                  const float* __restrict__ a_src, const float* __restrict__ a_dst,
                                  const float* __restrict__ denom, const float* __restrict__ h2,
                                  float* __restrict__ out2)
{
    const int e = blockIdx.x * blockDim.x + threadIdx.x;
    if (e >= ETOT) return;
    int s, d;
    if (!edge_sd(esrc, edst, e, s, d)) return;
    const float alpha = elog(a_src[s] + a_dst[d]) / (denom[d] + 1e-16f);
#pragma unroll
    for (int c = 0; c < NC; ++c)
        atomicAdd(&out2[d * NC + c], h2[s * NC + c] * alpha);
}

__global__ void final_kernel(const float* __restrict__ out2, const float* __restrict__ wc,
                             void* __restrict__ out, const int* __restrict__ flags)
{
    const int idx = blockIdx.x * blockDim.x + threadIdx.x;
    if (idx >= NN * NC) return;
    const int c = idx % NC;
    const float v = out2[idx] + wc[OB2 + c];
    if (flags[0]) ((bf16*)out)[idx] = __float2bfloat16(v);
    else          ((float*)out)[idx] = v;
}

extern "C" void kernel_launch(void* const* d_in, const int* in_sizes, int n_in,
                              void* d_out, int out_size, void* d_ws, size_t ws_size,
                              hipStream_t stream)
{
    const void* x        = d_in[0];
    const void* eidx     = d_in[1];
    const void* W1       = d_in[2];
    const void* att_src1 = d_in[3];
    const void* att_dst1 = d_in[4];
    const void* b1       = d_in[5];
    const void* W2       = d_in[6];
    const void* att_src2 = d_in[7];
    const void* att_dst2 = d_in[8];
    const void* b2       = d_in[9];

    float* ws = (float*)d_ws;
    int*   flags = (int*)ws;                                   // 16 slots
    int*   e32   = (int*)(ws + 16);                            // 2*EE = 1.6M slots
    float* wc    = ws + 16 + 2 * (size_t)EE;                   // 65536 slots (pad)
    bf16*  h1    = (bf16*)(ws + 16 + 2 * (size_t)EE + 65536);  // N*HC/2 = 3.2M slots
    float* dyn   = ws + 16 + 2 * (size_t)EE + 65536 + (size_t)NN * HC / 2;

    const int* esrc = e32;
    const int* edst = e32 + EE;

    const size_t FIXED = 16 + 2 * (size_t)EE + 65536 + (size_t)NN * HC / 2;
    const size_t FAST_SLOTS = FIXED + 2 * (size_t)NN * NH + (size_t)NN * NC + 2 * (size_t)NN
                            + (size_t)NN * NH + (size_t)NN * HC + NN + (size_t)NN * NC;
    const bool fast = (ws_size >= FAST_SLOTS * sizeof(float));

    detect_kernel<<<1, 256, 0, stream>>>((const unsigned short*)x, (const unsigned int*)eidx, flags);
    conv_edge_kernel<<<(2 * EE + 255) / 256, 256, 0, stream>>>(eidx, e32, flags);
    conv_w_kernel<<<(WTOT + 255) / 256, 256, 0, stream>>>(W1, att_src1, att_dst1, b1,
                                                          W2, att_src2, att_dst2, b2, wc, flags);

    if (fast) {
        float* a_src1 = dyn;                          // N*8
        float* a_dst1 = a_src1 + (size_t)NN * NH;     // N*8
        float* h2     = a_dst1 + (size_t)NN * NH;     // N*7
        float* a_src2 = h2 + (size_t)NN * NC;         // N
        float* a_dst2 = a_src2 + NN;                  // N
        float* denom1 = a_dst2 + NN;                  // N*8   (zeroed)
        float* out1   = denom1 + (size_t)NN * NH;     // N*128 (zeroed)
        float* denom2 = out1 + (size_t)NN * HC;       // N     (zeroed)
        float* out2   = denom2 + NN;                  // N*7   (zeroed)

        const size_t zf = (size_t)NN * NH + (size_t)NN * HC + NN + (size_t)NN * NC;
        hipMemsetAsync(denom1, 0, zf * sizeof(float), stream);

        gemm1_kernel<<<(NN + 127) / 128, 256, 0, stream>>>(x, wc, h1, flags);
        att1_kernel<<<(NN * NH + 255) / 256, 256, 0, stream>>>(h1, wc, a_src1, a_dst1);
        edge1_denom_kernel<<<(ETOT + 255) / 256, 256, 0, stream>>>(esrc, edst, a_src1, a_dst1, denom1);
        edge1_aggr_full_kernel<<<(ETOT + 1) / 2, 256, 0, stream>>>(esrc, edst, a_src1, a_dst1, denom1, h1, out1);
        bias_relu_kernel<<<(NN * HC + 255) / 256, 256, 0, stream>>>(out1, wc);
        gemm2_kernel<<<(NN + 31) / 32, 256, 0, stream>>>(out1, wc, h2);
        att2_kernel<<<(NN + 255) / 256, 256, 0, stream>>>(h2, wc, a_src2, a_dst2);
        edge2_denom_kernel<<<(ETOT + 255) / 256, 256, 0, stream>>>(esrc, edst, a_src2, a_dst2, denom2);
        edge2_aggr_kernel<<<(ETOT + 255) / 256, 256, 0, stream>>>(esrc, edst, a_src2, a_dst2, denom2, h2, out2);
        final_kernel<<<(NN * NC + 255) / 256, 256, 0, stream>>>(out2, wc, d_out, flags);
    } else {
        float* a_src1 = dyn;                          // N*8
        float* a_dst1 = a_src1 + (size_t)NN * NH;     // N*8
        float* a_src2 = a_dst1 + (size_t)NN * NH;     // N
        float* a_dst2 = a_src2 + NN;                  // N
        float* denom1 = a_dst2 + NN;                  // N*8   (zeroed)
        float* h2     = denom1 + (size_t)NN * NH;     // N*7   (zeroed, accumulated)
        float* denom2 = h2 + (size_t)NN * NC;         // N     (zeroed)
        float* out2   = denom2 + NN;                  // N*7   (zeroed)
        float* out1h  = out2 + (size_t)NN * NC;       // N*16  (zeroed per pass)

        const size_t zf = (size_t)NN * NH + (size_t)NN * NC + NN + (size_t)NN * NC
                        + (size_t)NN * CH;
        hipMemsetAsync(denom1, 0, zf * sizeof(float), stream);

        gemm1_kernel<<<(NN + 127) / 128, 256, 0, stream>>>(x, wc, h1, flags);
        att1_kernel<<<(NN * NH + 255) / 256, 256, 0, stream>>>(h1, wc, a_src1, a_dst1);
        edge1_denom_kernel<<<(ETOT + 255) / 256, 256, 0, stream>>>(esrc, edst, a_src1, a_dst1, denom1);
        for (int h = 0; h < NH; ++h) {
            if (h > 0)
                hipMemsetAsync(out1h, 0, (size_t)NN * CH * sizeof(float), stream);
            edge1_aggr_head_kernel<<<((size_t)ETOT * 16 + 255) / 256, 256, 0, stream>>>(
                esrc, edst, a_src1, a_dst1, denom1, h1, out1h, h);
            gemm2_head_kernel<<<(NN * 8 + 255) / 256, 256, 0, stream>>>(out1h, wc, h2, h);
        }
        att2_kernel<<<(NN + 255) / 256, 256, 0, stream>>>(h2, wc, a_src2, a_dst2);
        edge2_denom_kernel<<<(ETOT + 255) / 256, 256, 0, stream>>>(esrc, edst, a_src2, a_dst2, denom2);
        edge2_aggr_kernel<<<(ETOT + 255) / 256, 256, 0, stream>>>(esrc, edst, a_src2, a_dst2, denom2, h2, out2);
        final_kernel<<<(NN * NC + 255) / 256, 256, 0, stream>>>(out2, wc, d_out, flags);
    }
}

// Round 6
// 556.953 us; speedup vs baseline: 2.5414x; 2.5414x over previous
//
#include <hip/hip_runtime.h>
#include <hip/hip_bf16.h>

#define NN 50000
#define EE 800000
#define ETOT 850000   // EE + NN self-loops
#define FIN 500
#define HC 128        // 8 heads * 16 ch
#define NH 8
#define CH 16
#define NC 7

// canonical fp32 weight-buffer offsets
#define OW1  0
#define OAS1 64000
#define OAD1 64128
#define OB1  64256
#define OW2  64384
#define OAS2 65280
#define OAD2 65287
#define OB2  65294
#define WTOT 65301

typedef __hip_bfloat16 bf16;

__device__ __forceinline__ float b2f(const bf16 v) { return __bfloat162float(v); }
__device__ __forceinline__ float lrelu(float v) { return fmaxf(v, 0.2f * v); }
__device__ __forceinline__ float elog(float v) { return __expf(fminf(lrelu(v), 30.f)); }

// read edge index element i from raw buffer (int64 or int32 per flag)
__device__ __forceinline__ int eread(const void* __restrict__ eidx, long long i, int is64)
{
    if (is64) return (int)((const long long*)eidx)[i];
    return ((const int*)eidx)[i];
}

// ---------------- dtype detection ----------------
// flags[0]=1 if x is bf16, 0 if fp32.  flags[1]=1 if edge_index is int64, 0 if int32.
__global__ void detect_kernel(const unsigned short* __restrict__ xraw,
                              const unsigned int* __restrict__ eraw,
                              int* __restrict__ flags)
{
    __shared__ int s_insane, s_oddnz;
    if (threadIdx.x == 0) { s_insane = 0; s_oddnz = 0; }
    __syncthreads();
    int insane = 0;
    for (int i = threadIdx.x; i < 8192; i += 256) {
        const unsigned int bits = ((unsigned int)xraw[i]) << 16;
        const float v = __uint_as_float(bits);
        const float a = fabsf(v);
        const bool sane = (v == 0.0f) || (a >= 1e-30f && a <= 1e4f);
        if (!sane) insane++;
    }
    int oddnz = 0;
    for (int i = threadIdx.x; i < 512; i += 256) {
        if (eraw[2 * i + 1] != 0u) oddnz++;
    }
    atomicAdd(&s_insane, insane);
    atomicAdd(&s_oddnz, oddnz);
    __syncthreads();
    if (threadIdx.x == 0) {
        flags[0] = (s_insane < 256) ? 1 : 0;
        flags[1] = (s_oddnz == 0) ? 1 : 0;
    }
}

// ---------------- canonicalize all small weights to fp32 ----------------
__global__ void conv_w_kernel(const void* W1, const void* as1, const void* ad1, const void* b1,
                              const void* W2, const void* as2, const void* ad2, const void* b2,
                              float* __restrict__ wc, const int* __restrict__ flags)
{
    const int i = blockIdx.x * blockDim.x + threadIdx.x;
    if (i >= WTOT) return;
    const void* src; int off;
    if (i < OAS1)      { src = W1;  off = i - OW1; }
    else if (i < OAD1) { src = as1; off = i - OAS1; }
    else if (i < OB1)  { src = ad1; off = i - OAD1; }
    else if (i < OW2)  { src = b1;  off = i - OB1; }
    else if (i < OAS2) { src = W2;  off = i - OW2; }
    else if (i < OAD2) { src = as2; off = i - OAS2; }
    else if (i < OB2)  { src = ad2; off = i - OAD2; }
    else               { src = b2;  off = i - OB2; }
    float v;
    if (flags[0]) v = b2f(((const bf16*)src)[off]);
    else          v = ((const float*)src)[off];
    wc[i] = v;
}

// ---------------- CSR build: histogram of dst ----------------
__global__ void hist_kernel(const void* __restrict__ eidx, int* __restrict__ deg,
                            const int* __restrict__ flags)
{
    const int e = blockIdx.x * blockDim.x + threadIdx.x;
    if (e >= ETOT) return;
    int d;
    if (e < EE) d = eread(eidx, (long long)EE + e, flags[1]);
    else        d = e - EE;
    if ((unsigned)d < (unsigned)NN) atomicAdd(&deg[d], 1);
}

// ---------------- scan k1: per-256-chunk sums ----------------
__global__ void scan_k1_kernel(const int* __restrict__ deg, int* __restrict__ bsum)
{
    __shared__ int lds[256];
    const int i = blockIdx.x * 256 + threadIdx.x;
    lds[threadIdx.x] = (i < NN) ? deg[i] : 0;
    __syncthreads();
    for (int s = 128; s > 0; s >>= 1) {
        if (threadIdx.x < s) lds[threadIdx.x] += lds[threadIdx.x + s];
        __syncthreads();
    }
    if (threadIdx.x == 0) bsum[blockIdx.x] = lds[0];
}

// ---------------- scan k2: exclusive scan of 256 block sums (in place) ----------------
__global__ void scan_k2_kernel(int* __restrict__ bsum)
{
    __shared__ int a[256], b[256], orig[256];
    const int t = threadIdx.x;
    a[t] = bsum[t]; orig[t] = a[t];
    __syncthreads();
    int* cur = a; int* nxt = b;
    for (int off = 1; off < 256; off <<= 1) {
        nxt[t] = cur[t] + ((t >= off) ? cur[t - off] : 0);
        __syncthreads();
        int* tmp = cur; cur = nxt; nxt = tmp;
    }
    bsum[t] = cur[t] - orig[t];   // exclusive = inclusive - original
}

// ---------------- scan k3: per-chunk exclusive scan + block offset -> rowptr ----------------
__global__ void scan_k3_kernel(const int* __restrict__ deg, const int* __restrict__ bsum,
                               int* __restrict__ rowptr)
{
    __shared__ int a[256], b[256], own[256];
    const int t = threadIdx.x;
    const int i = blockIdx.x * 256 + t;
    const int v = (i < NN) ? deg[i] : 0;
    a[t] = v; own[t] = v;
    __syncthreads();
    int* cur = a; int* nxt = b;
    for (int off = 1; off < 256; off <<= 1) {
        nxt[t] = cur[t] + ((t >= off) ? cur[t - off] : 0);
        __syncthreads();
        int* tmp = cur; cur = nxt; nxt = tmp;
    }
    // exclusive start position; scatter_kernel advances rowptr[n] to the segment end
    if (i < NN) rowptr[i] = bsum[blockIdx.x] + cur[t] - own[t];
}

// ---------------- CSR scatter: rowptr[n] advances from start to end ----------------
__global__ void scatter_kernel(const void* __restrict__ eidx, int* __restrict__ rowptr,
                               int* __restrict__ esrc_sorted, const int* __restrict__ flags)
{
    const int e = blockIdx.x * blockDim.x + threadIdx.x;
    if (e >= ETOT) return;
    int s, d;
    if (e < EE) {
        s = eread(eidx, e, flags[1]);
        d = eread(eidx, (long long)EE + e, flags[1]);
    } else s = d = e - EE;
    if ((unsigned)s >= (unsigned)NN || (unsigned)d >= (unsigned)NN) return;
    const int pos = atomicAdd(&rowptr[d], 1);
    if ((unsigned)pos < (unsigned)ETOT) esrc_sorted[pos] = s;
}
// After scatter_kernel: rowptr[n] == end of segment n; start = (n==0 ? 0 : rowptr[n-1]).

// ---------------- GEMM1: h1[N,128](bf16) = x[N,500] @ W1[500,128] ----------------
__global__ __launch_bounds__(256) void gemm1_kernel(
    const void* __restrict__ x, const float* __restrict__ wc,
    bf16* __restrict__ h1, const int* __restrict__ flags)
{
    __shared__ float As[32][128];   // k-major: As[k][row]
    __shared__ float Bs[32][128];   // k-major: Bs[k][col]
    const int isbf = flags[0];
    const bf16*  xb = (const bf16*)x;
    const float* xf = (const float*)x;
    const int t  = threadIdx.x;
    const int tx = t & 15;
    const int ty = t >> 4;
    const int r0 = blockIdx.x * 128;

    float acc[8][8];
#pragma unroll
    for (int i = 0; i < 8; ++i)
#pragma unroll
        for (int j = 0; j < 8; ++j) acc[i][j] = 0.f;

    const int arow = t >> 1;
    const int aka  = (t & 1) * 16;
    const int bcol = t & 127;
    const int bkb  = (t >> 7) * 16;

    for (int k0 = 0; k0 < FIN; k0 += 32) {
        {
            const int grow = r0 + arow;
            const bool rowok = (grow < NN);
            const size_t base = (size_t)grow * FIN;
            if (isbf) {
#pragma unroll
                for (int j = 0; j < 16; ++j) {
                    const int k = k0 + aka + j;
                    float v = 0.f;
                    if (rowok && k < FIN) v = b2f(xb[base + k]);
                    As[aka + j][arow] = v;
                }
            } else {
#pragma unroll
                for (int j = 0; j < 16; ++j) {
                    const int k = k0 + aka + j;
                    float v = 0.f;
                    if (rowok && k < FIN) v = xf[base + k];
                    As[aka + j][arow] = v;
                }
            }
        }
#pragma unroll
        for (int j = 0; j < 16; ++j) {
            const int k = k0 + bkb + j;
            Bs[bkb + j][bcol] = (k < FIN) ? wc[OW1 + k * HC + bcol] : 0.f;
        }
        __syncthreads();
#pragma unroll
        for (int kk = 0; kk < 32; ++kk) {
            const float4 a0 = *(const float4*)&As[kk][8 * ty];
            const float4 a1 = *(const float4*)&As[kk][8 * ty + 4];
            const float4 b0 = *(const float4*)&Bs[kk][4 * tx];
            const float4 b1 = *(const float4*)&Bs[kk][64 + 4 * tx];
            const float av[8] = {a0.x, a0.y, a0.z, a0.w, a1.x, a1.y, a1.z, a1.w};
            const float bv[8] = {b0.x, b0.y, b0.z, b0.w, b1.x, b1.y, b1.z, b1.w};
#pragma unroll
            for (int i = 0; i < 8; ++i)
#pragma unroll
                for (int j = 0; j < 8; ++j) acc[i][j] += av[i] * bv[j];
        }
        __syncthreads();
    }
#pragma unroll
    for (int i = 0; i < 8; ++i) {
        const int row = r0 + 8 * ty + i;
        if (row < NN) {
            bf16* hp = h1 + (size_t)row * HC;
#pragma unroll
            for (int j = 0; j < 4; ++j) {
                hp[4 * tx + j]      = __float2bfloat16(acc[i][j]);
                hp[64 + 4 * tx + j] = __float2bfloat16(acc[i][4 + j]);
            }
        }
    }
}

// ---------------- per-node attention logits, layer 1 (bf16x2 unpack) ----------------
__global__ void att1_kernel(const bf16* __restrict__ h1, const float* __restrict__ wc,
                            float* __restrict__ a_src, float* __restrict__ a_dst)
{
    const int idx = blockIdx.x * blockDim.x + threadIdx.x;   // n*8 + h
    if (idx >= NN * NH) return;
    const int h = idx & 7;
    const unsigned int* hp = (const unsigned int*)(h1 + (size_t)(idx >> 3) * HC + h * CH);
    float s = 0.f, d = 0.f;
#pragma unroll
    for (int u = 0; u < 8; ++u) {
        const unsigned int w = hp[u];
        const float lo = __uint_as_float(w << 16);
        const float hi = __uint_as_float(w & 0xffff0000u);
        s += lo * wc[OAS1 + h * CH + 2 * u] + hi * wc[OAS1 + h * CH + 2 * u + 1];
        d += lo * wc[OAD1 + h * CH + 2 * u] + hi * wc[OAD1 + h * CH + 2 * u + 1];
    }
    a_src[idx] = s;
    a_dst[idx] = d;
}

// ---------------- layer-1 fused softmax+aggregation: one wave per node ----------------
// lane L handles channels 2L, 2L+1 (head = L>>3); numerator recomputed per edge,
// denominator accumulated in the same loop -> single pass, no atomics.
__global__ __launch_bounds__(256) void gather1_kernel(
    const int* __restrict__ rowptr, const int* __restrict__ esrc_sorted,
    const float* __restrict__ a_src, const float* __restrict__ a_dst,
    const bf16* __restrict__ h1, float* __restrict__ out1)
{
    const int node = blockIdx.x * 4 + (threadIdx.x >> 6);
    if (node >= NN) return;
    const int lane = threadIdx.x & 63;
    const int h = lane >> 3;
    const float ad = a_dst[node * NH + h];
    const int start = (node == 0) ? 0 : rowptr[node - 1];
    const int end   = rowptr[node];
    float acc0 = 0.f, acc1 = 0.f, den = 0.f;
    for (int i = start; i < end; ++i) {
        const int s = esrc_sorted[i];
        const float num = elog(a_src[s * NH + h] + ad);
        const unsigned int w = *(const unsigned int*)(h1 + (size_t)s * HC + 2 * lane);
        acc0 += num * __uint_as_float(w << 16);
        acc1 += num * __uint_as_float(w & 0xffff0000u);
        den  += num;
    }
    const float inv = 1.f / (den + 1e-16f);
    float* op = out1 + (size_t)node * HC + 2 * lane;
    op[0] = acc0 * inv;
    op[1] = acc1 * inv;
}

// ---------------- GEMM2 with fused bias+relu: h2[N,7] = relu(out1+b1) @ W2 ----------------
__global__ __launch_bounds__(256) void gemm2_kernel(
    const float* __restrict__ out1, const float* __restrict__ wc, float* __restrict__ h2)
{
    __shared__ float W2s[HC * NC];
    __shared__ float B1s[HC];
    for (int i = threadIdx.x; i < HC * NC; i += 256) W2s[i] = wc[OW2 + i];
    if (threadIdx.x < HC) B1s[threadIdx.x] = wc[OB1 + threadIdx.x];
    __syncthreads();
    const int nl = threadIdx.x >> 3;
    const int c  = threadIdx.x & 7;
    const int node = blockIdx.x * 32 + nl;
    if (c >= NC || node >= NN) return;
    const float* hp = out1 + (size_t)node * HC;
    float acc = 0.f;
#pragma unroll
    for (int k4 = 0; k4 < 32; ++k4) {
        const float4 hv = *(const float4*)&hp[4 * k4];
        acc += fmaxf(hv.x + B1s[4 * k4 + 0], 0.f) * W2s[(4 * k4 + 0) * NC + c];
        acc += fmaxf(hv.y + B1s[4 * k4 + 1], 0.f) * W2s[(4 * k4 + 1) * NC + c];
        acc += fmaxf(hv.z + B1s[4 * k4 + 2], 0.f) * W2s[(4 * k4 + 2) * NC + c];
        acc += fmaxf(hv.w + B1s[4 * k4 + 3], 0.f) * W2s[(4 * k4 + 3) * NC + c];
    }
    h2[node * NC + c] = acc;
}

// ---------------- per-node attention logits, layer 2 ----------------
__global__ void att2_kernel(const float* __restrict__ h2, const float* __restrict__ wc,
                            float* __restrict__ a_src, float* __restrict__ a_dst)
{
    const int n = blockIdx.x * blockDim.x + threadIdx.x;
    if (n >= NN) return;
    float s = 0.f, d = 0.f;
#pragma unroll
    for (int c = 0; c < NC; ++c) {
        const float hv = h2[n * NC + c];
        s += hv * wc[OAS2 + c];
        d += hv * wc[OAD2 + c];
    }
    a_src[n] = s;
    a_dst[n] = d;
}

// ---------------- layer-2 fused softmax+aggregation+bias+store: 8 lanes per node ----------------
__global__ __launch_bounds__(256) void gather2_kernel(
    const int* __restrict__ rowptr, const int* __restrict__ esrc_sorted,
    const float* __restrict__ a_src, const float* __restrict__ a_dst,
    const float* __restrict__ h2, const float* __restrict__ wc,
    void* __restrict__ out, const int* __restrict__ flags)
{
    const int node = blockIdx.x * 32 + (threadIdx.x >> 3);
    if (node >= NN) return;
    const int c = threadIdx.x & 7;
    const float ad = a_dst[node];
    const int start = (node == 0) ? 0 : rowptr[node - 1];
    const int end   = rowptr[node];
    float acc = 0.f, den = 0.f;
    for (int i = start; i < end; ++i) {
        const int s = esrc_sorted[i];
        const float num = elog(a_src[s] + ad);
        den += num;
        if (c < NC) acc += num * h2[s * NC + c];
    }
    if (c >= NC) return;
    const float v = acc / (den + 1e-16f) + wc[OB2 + c];
    if (flags[0]) ((bf16*)out)[node * NC + c] = __float2bfloat16(v);
    else          ((float*)out)[node * NC + c] = v;
}

extern "C" void kernel_launch(void* const* d_in, const int* in_sizes, int n_in,
                              void* d_out, int out_size, void* d_ws, size_t ws_size,
                              hipStream_t stream)
{
    const void* x        = d_in[0];
    const void* eidx     = d_in[1];
    const void* W1       = d_in[2];
    const void* att_src1 = d_in[3];
    const void* att_dst1 = d_in[4];
    const void* b1       = d_in[5];
    const void* W2       = d_in[6];
    const void* att_src2 = d_in[7];
    const void* att_dst2 = d_in[8];
    const void* b2       = d_in[9];

    float* ws = (float*)d_ws;
    size_t o = 0;
    int*   flags  = (int*)(ws + o);  o += 16;
    float* wc     = ws + o;          o += 65312;            // WTOT padded
    int*   deg    = (int*)(ws + o);  o += 50000;
    int*   rowptr = (int*)(ws + o);  o += 50016;
    int*   bsum   = (int*)(ws + o);  o += 256;
    int*   esrt   = (int*)(ws + o);  o += 850000;           // CSR-sorted src ids
    bf16*  h1     = (bf16*)(ws + o); o += (size_t)NN * HC / 2;
    float* a_src1 = ws + o;          o += (size_t)NN * NH;
    float* a_dst1 = ws + o;          o += (size_t)NN * NH;
    float* out1   = ws + o;          o += (size_t)NN * HC;
    float* h2     = ws + o;          o += (size_t)NN * NC;
    float* a_src2 = ws + o;          o += NN;
    float* a_dst2 = ws + o;          o += NN;
    // total ~11.9M floats = 47.5 MB < 53.3 MB proven available (fast path ran in R3)

    detect_kernel<<<1, 256, 0, stream>>>((const unsigned short*)x, (const unsigned int*)eidx, flags);
    conv_w_kernel<<<(WTOT + 255) / 256, 256, 0, stream>>>(W1, att_src1, att_dst1, b1,
                                                          W2, att_src2, att_dst2, b2, wc, flags);
    hipMemsetAsync(deg, 0, (size_t)NN * sizeof(int), stream);
    hist_kernel<<<(ETOT + 255) / 256, 256, 0, stream>>>(eidx, deg, flags);
    scan_k1_kernel<<<(NN + 255) / 256, 256, 0, stream>>>(deg, bsum);
    scan_k2_kernel<<<1, 256, 0, stream>>>(bsum);
    scan_k3_kernel<<<(NN + 255) / 256, 256, 0, stream>>>(deg, bsum, rowptr);
    scatter_kernel<<<(ETOT + 255) / 256, 256, 0, stream>>>(eidx, rowptr, esrt, flags);

    gemm1_kernel<<<(NN + 127) / 128, 256, 0, stream>>>(x, wc, h1, flags);
    att1_kernel<<<(NN * NH + 255) / 256, 256, 0, stream>>>(h1, wc, a_src1, a_dst1);
    gather1_kernel<<<(NN + 3) / 4, 256, 0, stream>>>(rowptr, esrt, a_src1, a_dst1, h1, out1);
    gemm2_kernel<<<(NN + 31) / 32, 256, 0, stream>>>(out1, wc, h2);
    att2_kernel<<<(NN + 255) / 256, 256, 0, stream>>>(h2, wc, a_src2, a_dst2);
    gather2_kernel<<<(NN + 31) / 32, 256, 0, stream>>>(rowptr, esrt, a_src2, a_dst2, h2, wc, d_out, flags);
}

// Round 7
// 433.102 us; speedup vs baseline: 3.2682x; 1.2860x over previous
//
#include <hip/hip_runtime.h>
#include <hip/hip_bf16.h>

#define NN 50000
#define EE 800000
#define ETOT 850000   // EE + NN self-loops
#define FIN 500
#define HC 128        // 8 heads * 16 ch
#define NH 8
#define CH 16
#define NC 7

// canonical fp32 weight-buffer offsets
#define OW1  0
#define OAS1 64000
#define OAD1 64128
#define OB1  64256
#define OW2  64384
#define OAS2 65280
#define OAD2 65287
#define OB2  65294
#define WTOT 65301

// MFMA gemm1 tiling
#define GR1  64    // rows per block
#define GK   32    // k per step
#define KPAD 512   // FIN padded
#define ASTR 40    // A LDS stride (shorts): 20*m mod 32 -> 2-way aliasing (free)
#define BSTR 40    // B LDS stride (shorts)

typedef __hip_bfloat16 bf16;
typedef __attribute__((ext_vector_type(8))) short short8;
typedef __attribute__((ext_vector_type(4))) float f32x4;

__device__ __forceinline__ float b2f(const bf16 v) { return __bfloat162float(v); }
__device__ __forceinline__ float lrelu(float v) { return fmaxf(v, 0.2f * v); }
__device__ __forceinline__ float elog(float v) { return __expf(fminf(lrelu(v), 30.f)); }
__device__ __forceinline__ unsigned short f2bu(float f)
{
    bf16 h = __float2bfloat16(f);
    return *(unsigned short*)&h;
}

// read edge index element i from raw buffer (int64 or int32 per flag)
__device__ __forceinline__ int eread(const void* __restrict__ eidx, long long i, int is64)
{
    if (is64) return (int)((const long long*)eidx)[i];
    return ((const int*)eidx)[i];
}

// ---------------- dtype detection ----------------
__global__ void detect_kernel(const unsigned short* __restrict__ xraw,
                              const unsigned int* __restrict__ eraw,
                              int* __restrict__ flags)
{
    __shared__ int s_insane, s_oddnz;
    if (threadIdx.x == 0) { s_insane = 0; s_oddnz = 0; }
    __syncthreads();
    int insane = 0;
    for (int i = threadIdx.x; i < 8192; i += 256) {
        const unsigned int bits = ((unsigned int)xraw[i]) << 16;
        const float v = __uint_as_float(bits);
        const float a = fabsf(v);
        const bool sane = (v == 0.0f) || (a >= 1e-30f && a <= 1e4f);
        if (!sane) insane++;
    }
    int oddnz = 0;
    for (int i = threadIdx.x; i < 512; i += 256) {
        if (eraw[2 * i + 1] != 0u) oddnz++;
    }
    atomicAdd(&s_insane, insane);
    atomicAdd(&s_oddnz, oddnz);
    __syncthreads();
    if (threadIdx.x == 0) {
        flags[0] = (s_insane < 256) ? 1 : 0;
        flags[1] = (s_oddnz == 0) ? 1 : 0;
    }
}

// ---------------- canonicalize all small weights to fp32 ----------------
__global__ void conv_w_kernel(const void* W1, const void* as1, const void* ad1, const void* b1,
                              const void* W2, const void* as2, const void* ad2, const void* b2,
                              float* __restrict__ wc, const int* __restrict__ flags)
{
    const int i = blockIdx.x * blockDim.x + threadIdx.x;
    if (i >= WTOT) return;
    const void* src; int off;
    if (i < OAS1)      { src = W1;  off = i - OW1; }
    else if (i < OAD1) { src = as1; off = i - OAS1; }
    else if (i < OB1)  { src = ad1; off = i - OAD1; }
    else if (i < OW2)  { src = b1;  off = i - OB1; }
    else if (i < OAS2) { src = W2;  off = i - OW2; }
    else if (i < OAD2) { src = as2; off = i - OAS2; }
    else if (i < OB2)  { src = ad2; off = i - OAD2; }
    else               { src = b2;  off = i - OB2; }
    float v;
    if (flags[0]) v = b2f(((const bf16*)src)[off]);
    else          v = ((const float*)src)[off];
    wc[i] = v;
}

// ---------------- W1 -> bf16 transposed+padded [128 cols][512 k] ----------------
__global__ void conv_w1t_kernel(const void* __restrict__ W1, unsigned short* __restrict__ w1t,
                                const int* __restrict__ flags)
{
    const int i = blockIdx.x * blockDim.x + threadIdx.x;   // col*512 + k
    if (i >= HC * KPAD) return;
    const int col = i >> 9;
    const int k   = i & (KPAD - 1);
    float v = 0.f;
    if (k < FIN) {
        if (flags[0]) v = b2f(((const bf16*)W1)[k * HC + col]);
        else          v = ((const float*)W1)[k * HC + col];
    }
    w1t[i] = f2bu(v);
}

// ---------------- CSR build: histogram of dst ----------------
__global__ void hist_kernel(const void* __restrict__ eidx, int* __restrict__ deg,
                            const int* __restrict__ flags)
{
    const int e = blockIdx.x * blockDim.x + threadIdx.x;
    if (e >= ETOT) return;
    int d;
    if (e < EE) d = eread(eidx, (long long)EE + e, flags[1]);
    else        d = e - EE;
    if ((unsigned)d < (unsigned)NN) atomicAdd(&deg[d], 1);
}

// ---------------- scan k1: per-256-chunk sums ----------------
__global__ void scan_k1_kernel(const int* __restrict__ deg, int* __restrict__ bsum)
{
    __shared__ int lds[256];
    const int i = blockIdx.x * 256 + threadIdx.x;
    lds[threadIdx.x] = (i < NN) ? deg[i] : 0;
    __syncthreads();
    for (int s = 128; s > 0; s >>= 1) {
        if (threadIdx.x < s) lds[threadIdx.x] += lds[threadIdx.x + s];
        __syncthreads();
    }
    if (threadIdx.x == 0) bsum[blockIdx.x] = lds[0];
}

// ---------------- scan k2: exclusive scan of 256 block sums ----------------
__global__ void scan_k2_kernel(int* __restrict__ bsum)
{
    __shared__ int a[256], b[256], orig[256];
    const int t = threadIdx.x;
    a[t] = bsum[t]; orig[t] = a[t];
    __syncthreads();
    int* cur = a; int* nxt = b;
    for (int off = 1; off < 256; off <<= 1) {
        nxt[t] = cur[t] + ((t >= off) ? cur[t - off] : 0);
        __syncthreads();
        int* tmp = cur; cur = nxt; nxt = tmp;
    }
    bsum[t] = cur[t] - orig[t];
}

// ---------------- scan k3: per-chunk exclusive scan + block offset -> rowptr ----------------
__global__ void scan_k3_kernel(const int* __restrict__ deg, const int* __restrict__ bsum,
                               int* __restrict__ rowptr)
{
    __shared__ int a[256], b[256], own[256];
    const int t = threadIdx.x;
    const int i = blockIdx.x * 256 + t;
    const int v = (i < NN) ? deg[i] : 0;
    a[t] = v; own[t] = v;
    __syncthreads();
    int* cur = a; int* nxt = b;
    for (int off = 1; off < 256; off <<= 1) {
        nxt[t] = cur[t] + ((t >= off) ? cur[t - off] : 0);
        __syncthreads();
        int* tmp = cur; cur = nxt; nxt = tmp;
    }
    if (i < NN) rowptr[i] = bsum[blockIdx.x] + cur[t] - own[t];
}

// ---------------- CSR scatter: rowptr[n] advances from start to end ----------------
__global__ void scatter_kernel(const void* __restrict__ eidx, int* __restrict__ rowptr,
                               int* __restrict__ esrc_sorted, const int* __restrict__ flags)
{
    const int e = blockIdx.x * blockDim.x + threadIdx.x;
    if (e >= ETOT) return;
    int s, d;
    if (e < EE) {
        s = eread(eidx, e, flags[1]);
        d = eread(eidx, (long long)EE + e, flags[1]);
    } else s = d = e - EE;
    if ((unsigned)s >= (unsigned)NN || (unsigned)d >= (unsigned)NN) return;
    const int pos = atomicAdd(&rowptr[d], 1);
    if ((unsigned)pos < (unsigned)ETOT) esrc_sorted[pos] = s;
}
// After scatter_kernel: rowptr[n] == end of segment n; start = (n==0 ? 0 : rowptr[n-1]).

// ---------------- GEMM1 (MFMA bf16): h1[N,128] = x[N,500] @ W1[500,128] ----------------
// 64x128 block tile, 4 waves each 32x64 (2 A-frags + 4 B-frags + 8 MFMA per K-step).
__global__ __launch_bounds__(256) void gemm1_mfma_kernel(
    const void* __restrict__ x, const unsigned short* __restrict__ w1t,
    bf16* __restrict__ h1, const int* __restrict__ flags)
{
    __shared__ unsigned short Asl[GR1 * ASTR];   // 64 rows, k-contig, stride 40
    __shared__ unsigned short Bsl[HC * BSTR];    // 128 cols, k-contig, stride 40

    const int t    = threadIdx.x;
    const int wv   = t >> 6;
    const int lane = t & 63;
    const int m15  = lane & 15;
    const int quad = lane >> 4;
    const int r0   = blockIdx.x * GR1;
    const int isbf = flags[0];
    const float* xf = (const float*)x;
    const bf16*  xb = (const bf16*)x;

    const int wr  = (wv >> 1) * 32;   // wave row offset within block: 0 / 32
    const int wcb = (wv & 1) * 64;    // wave col offset: 0 / 64

    f32x4 acc[2][4];
#pragma unroll
    for (int i = 0; i < 2; ++i)
#pragma unroll
        for (int j = 0; j < 4; ++j) acc[i][j] = (f32x4){0.f, 0.f, 0.f, 0.f};

    const int arow = t >> 2;          // 0..63
    const int akk  = (t & 3) * 8;     // 0,8,16,24
    const int bcol = t & 127;
    const int bks  = (t >> 7) * 16;   // 0 or 16

    for (int kt = 0; kt < 16; ++kt) {
        const int k0 = kt * GK;
        // ---- stage A: x[r0+arow][k0+akk .. +8] -> bf16 LDS ----
        {
            const int grow = r0 + arow;
            if (!isbf && grow < NN && (k0 + akk + 8) <= FIN) {
                const size_t base = (size_t)grow * FIN + k0 + akk;
                const float4 v0 = *(const float4*)(xf + base);
                const float4 v1 = *(const float4*)(xf + base + 4);
                uint4 pk;
                pk.x = (unsigned)f2bu(v0.x) | ((unsigned)f2bu(v0.y) << 16);
                pk.y = (unsigned)f2bu(v0.z) | ((unsigned)f2bu(v0.w) << 16);
                pk.z = (unsigned)f2bu(v1.x) | ((unsigned)f2bu(v1.y) << 16);
                pk.w = (unsigned)f2bu(v1.z) | ((unsigned)f2bu(v1.w) << 16);
                *(uint4*)&Asl[arow * ASTR + akk] = pk;
            } else {
#pragma unroll
                for (int j = 0; j < 8; ++j) {
                    const int k = k0 + akk + j;
                    float v = 0.f;
                    if (grow < NN && k < FIN)
                        v = isbf ? b2f(xb[(size_t)grow * FIN + k]) : xf[(size_t)grow * FIN + k];
                    Asl[arow * ASTR + akk + j] = f2bu(v);
                }
            }
        }
        // ---- stage B: w1t[bcol][k0+bks .. +16] -> LDS (already bf16, padded) ----
        {
            const unsigned short* gp = w1t + (size_t)bcol * KPAD + k0 + bks;
            *(uint4*)&Bsl[bcol * BSTR + bks]     = *(const uint4*)gp;
            *(uint4*)&Bsl[bcol * BSTR + bks + 8] = *(const uint4*)(gp + 8);
        }
        __syncthreads();

        const int ak = quad * 8;
        const short8 a0 = *(const short8*)&Asl[(wr + m15) * ASTR + ak];
        const short8 a1 = *(const short8*)&Asl[(wr + 16 + m15) * ASTR + ak];
#pragma unroll
        for (int ct = 0; ct < 4; ++ct) {
            const short8 b = *(const short8*)&Bsl[(wcb + ct * 16 + m15) * BSTR + ak];
            acc[0][ct] = __builtin_amdgcn_mfma_f32_16x16x32_bf16(a0, b, acc[0][ct], 0, 0, 0);
            acc[1][ct] = __builtin_amdgcn_mfma_f32_16x16x32_bf16(a1, b, acc[1][ct], 0, 0, 0);
        }
        __syncthreads();
    }

    // epilogue: C/D layout col=lane&15, row=quad*4+reg
#pragma unroll
    for (int rt = 0; rt < 2; ++rt) {
#pragma unroll
        for (int reg = 0; reg < 4; ++reg) {
            const int row = r0 + wr + rt * 16 + quad * 4 + reg;
            if (row < NN) {
                bf16* hp = h1 + (size_t)row * HC;
#pragma unroll
                for (int ct = 0; ct < 4; ++ct)
                    hp[wcb + ct * 16 + m15] = __float2bfloat16(acc[rt][ct][reg]);
            }
        }
    }
}

// ---------------- per-node attention logits, layer 1 (bf16x2 unpack) ----------------
__global__ void att1_kernel(const bf16* __restrict__ h1, const float* __restrict__ wc,
                            float* __restrict__ a_src, float* __restrict__ a_dst)
{
    const int idx = blockIdx.x * blockDim.x + threadIdx.x;   // n*8 + h
    if (idx >= NN * NH) return;
    const int h = idx & 7;
    const unsigned int* hp = (const unsigned int*)(h1 + (size_t)(idx >> 3) * HC + h * CH);
    float s = 0.f, d = 0.f;
#pragma unroll
    for (int u = 0; u < 8; ++u) {
        const unsigned int w = hp[u];
        const float lo = __uint_as_float(w << 16);
        const float hi = __uint_as_float(w & 0xffff0000u);
        s += lo * wc[OAS1 + h * CH + 2 * u] + hi * wc[OAS1 + h * CH + 2 * u + 1];
        d += lo * wc[OAD1 + h * CH + 2 * u] + hi * wc[OAD1 + h * CH + 2 * u + 1];
    }
    a_src[idx] = s;
    a_dst[idx] = d;
}

// ---------------- layer-1 fused softmax+aggregation: one wave per node ----------------
__global__ __launch_bounds__(256) void gather1_kernel(
    const int* __restrict__ rowptr, const int* __restrict__ esrc_sorted,
    const float* __restrict__ a_src, const float* __restrict__ a_dst,
    const bf16* __restrict__ h1, float* __restrict__ out1)
{
    const int node = blockIdx.x * 4 + (threadIdx.x >> 6);
    if (node >= NN) return;
    const int lane = threadIdx.x & 63;
    const int h = lane >> 3;
    const float ad = a_dst[node * NH + h];
    const int start = (node == 0) ? 0 : rowptr[node - 1];
    const int end   = rowptr[node];
    float acc0 = 0.f, acc1 = 0.f, den = 0.f;
    for (int i = start; i < end; ++i) {
        const int s = esrc_sorted[i];
        const float num = elog(a_src[s * NH + h] + ad);
        const unsigned int w = *(const unsigned int*)(h1 + (size_t)s * HC + 2 * lane);
        acc0 += num * __uint_as_float(w << 16);
        acc1 += num * __uint_as_float(w & 0xffff0000u);
        den  += num;
    }
    const float inv = 1.f / (den + 1e-16f);
    float* op = out1 + (size_t)node * HC + 2 * lane;
    op[0] = acc0 * inv;
    op[1] = acc1 * inv;
}

// ---------------- GEMM2 with fused bias+relu ----------------
__global__ __launch_bounds__(256) void gemm2_kernel(
    const float* __restrict__ out1, const float* __restrict__ wc, float* __restrict__ h2)
{
    __shared__ float W2s[HC * NC];
    __shared__ float B1s[HC];
    for (int i = threadIdx.x; i < HC * NC; i += 256) W2s[i] = wc[OW2 + i];
    if (threadIdx.x < HC) B1s[threadIdx.x] = wc[OB1 + threadIdx.x];
    __syncthreads();
    const int nl = threadIdx.x >> 3;
    const int c  = threadIdx.x & 7;
    const int node = blockIdx.x * 32 + nl;
    if (c >= NC || node >= NN) return;
    const float* hp = out1 + (size_t)node * HC;
    float acc = 0.f;
#pragma unroll
    for (int k4 = 0; k4 < 32; ++k4) {
        const float4 hv = *(const float4*)&hp[4 * k4];
        acc += fmaxf(hv.x + B1s[4 * k4 + 0], 0.f) * W2s[(4 * k4 + 0) * NC + c];
        acc += fmaxf(hv.y + B1s[4 * k4 + 1], 0.f) * W2s[(4 * k4 + 1) * NC + c];
        acc += fmaxf(hv.z + B1s[4 * k4 + 2], 0.f) * W2s[(4 * k4 + 2) * NC + c];
        acc += fmaxf(hv.w + B1s[4 * k4 + 3], 0.f) * W2s[(4 * k4 + 3) * NC + c];
    }
    h2[node * NC + c] = acc;
}

// ---------------- per-node attention logits, layer 2 ----------------
__global__ void att2_kernel(const float* __restrict__ h2, const float* __restrict__ wc,
                            float* __restrict__ a_src, float* __restrict__ a_dst)
{
    const int n = blockIdx.x * blockDim.x + threadIdx.x;
    if (n >= NN) return;
    float s = 0.f, d = 0.f;
#pragma unroll
    for (int c = 0; c < NC; ++c) {
        const float hv = h2[n * NC + c];
        s += hv * wc[OAS2 + c];
        d += hv * wc[OAD2 + c];
    }
    a_src[n] = s;
    a_dst[n] = d;
}

// ---------------- layer-2 fused softmax+aggregation+bias+store ----------------
__global__ __launch_bounds__(256) void gather2_kernel(
    const int* __restrict__ rowptr, const int* __restrict__ esrc_sorted,
    const float* __restrict__ a_src, const float* __restrict__ a_dst,
    const float* __restrict__ h2, const float* __restrict__ wc,
    void* __restrict__ out, const int* __restrict__ flags)
{
    const int node = blockIdx.x * 32 + (threadIdx.x >> 3);
    if (node >= NN) return;
    const int c = threadIdx.x & 7;
    const float ad = a_dst[node];
    const int start = (node == 0) ? 0 : rowptr[node - 1];
    const int end   = rowptr[node];
    float acc = 0.f, den = 0.f;
    for (int i = start; i < end; ++i) {
        const int s = esrc_sorted[i];
        const float num = elog(a_src[s] + ad);
        den += num;
        if (c < NC) acc += num * h2[s * NC + c];
    }
    if (c >= NC) return;
    const float v = acc / (den + 1e-16f) + wc[OB2 + c];
    if (flags[0]) ((bf16*)out)[node * NC + c] = __float2bfloat16(v);
    else          ((float*)out)[node * NC + c] = v;
}

extern "C" void kernel_launch(void* const* d_in, const int* in_sizes, int n_in,
                              void* d_out, int out_size, void* d_ws, size_t ws_size,
                              hipStream_t stream)
{
    const void* x        = d_in[0];
    const void* eidx     = d_in[1];
    const void* W1       = d_in[2];
    const void* att_src1 = d_in[3];
    const void* att_dst1 = d_in[4];
    const void* b1       = d_in[5];
    const void* W2       = d_in[6];
    const void* att_src2 = d_in[7];
    const void* att_dst2 = d_in[8];
    const void* b2       = d_in[9];

    float* ws = (float*)d_ws;
    size_t o = 0;
    int*   flags  = (int*)(ws + o);            o += 16;
    float* wc     = ws + o;                    o += 65312;
    unsigned short* w1t = (unsigned short*)(ws + o); o += (HC * KPAD) / 2;   // bf16 [128][512]
    int*   deg    = (int*)(ws + o);            o += 50000;
    int*   rowptr = (int*)(ws + o);            o += 50016;
    int*   bsum   = (int*)(ws + o);            o += 256;
    int*   esrt   = (int*)(ws + o);            o += 850000;
    bf16*  h1     = (bf16*)(ws + o);           o += (size_t)NN * HC / 2;
    float* a_src1 = ws + o;                    o += (size_t)NN * NH;
    float* a_dst1 = ws + o;                    o += (size_t)NN * NH;
    float* out1   = ws + o;                    o += (size_t)NN * HC;
    float* h2     = ws + o;                    o += (size_t)NN * NC;
    float* a_src2 = ws + o;                    o += NN;
    float* a_dst2 = ws + o;                    o += NN;
    // total ~11.96M floats = 47.9 MB < 53.3 MB proven available

    detect_kernel<<<1, 256, 0, stream>>>((const unsigned short*)x, (const unsigned int*)eidx, flags);
    conv_w_kernel<<<(WTOT + 255) / 256, 256, 0, stream>>>(W1, att_src1, att_dst1, b1,
                                                          W2, att_src2, att_dst2, b2, wc, flags);
    conv_w1t_kernel<<<(HC * KPAD + 255) / 256, 256, 0, stream>>>(W1, w1t, flags);
    hipMemsetAsync(deg, 0, (size_t)NN * sizeof(int), stream);
    hist_kernel<<<(ETOT + 255) / 256, 256, 0, stream>>>(eidx, deg, flags);
    scan_k1_kernel<<<(NN + 255) / 256, 256, 0, stream>>>(deg, bsum);
    scan_k2_kernel<<<1, 256, 0, stream>>>(bsum);
    scan_k3_kernel<<<(NN + 255) / 256, 256, 0, stream>>>(deg, bsum, rowptr);
    scatter_kernel<<<(ETOT + 255) / 256, 256, 0, stream>>>(eidx, rowptr, esrt, flags);

    gemm1_mfma_kernel<<<(NN + GR1 - 1) / GR1, 256, 0, stream>>>(x, w1t, h1, flags);
    att1_kernel<<<(NN * NH + 255) / 256, 256, 0, stream>>>(h1, wc, a_src1, a_dst1);
    gather1_kernel<<<(NN + 3) / 4, 256, 0, stream>>>(rowptr, esrt, a_src1, a_dst1, h1, out1);
    gemm2_kernel<<<(NN + 31) / 32, 256, 0, stream>>>(out1, wc, h2);
    att2_kernel<<<(NN + 255) / 256, 256, 0, stream>>>(h2, wc, a_src2, a_dst2);
    gather2_kernel<<<(NN + 31) / 32, 256, 0, stream>>>(rowptr, esrt, a_src2, a_dst2, h2, wc, d_out, flags);
}

// Round 8
// 382.637 us; speedup vs baseline: 3.6992x; 1.1319x over previous
//
#include <hip/hip_runtime.h>
#include <hip/hip_bf16.h>

#define NN 50000
#define EE 800000
#define ETOT 850000   // EE + NN self-loops
#define FIN 500
#define HC 128        // 8 heads * 16 ch
#define NH 8
#define CH 16
#define NC 7

// canonical fp32 weight-buffer offsets
#define OW1  0
#define OAS1 64000
#define OAD1 64128
#define OB1  64256
#define OW2  64384
#define OAS2 65280
#define OAD2 65287
#define OB2  65294
#define WTOT 65301

// MFMA gemm1 tiling
#define GR1  64    // rows per block
#define GK   32    // k per step
#define KPAD 512   // FIN padded
#define ASTR 40    // A LDS stride (shorts): 2-way bank aliasing (free)
#define BSTR 40

typedef __hip_bfloat16 bf16;
typedef __attribute__((ext_vector_type(8))) short short8;
typedef __attribute__((ext_vector_type(4))) float f32x4;

__device__ __forceinline__ float b2f(const bf16 v) { return __bfloat162float(v); }
__device__ __forceinline__ float lrelu(float v) { return fmaxf(v, 0.2f * v); }
__device__ __forceinline__ float elog(float v) { return __expf(fminf(lrelu(v), 30.f)); }
__device__ __forceinline__ float blo(unsigned w) { return __uint_as_float(w << 16); }
__device__ __forceinline__ float bhi(unsigned w) { return __uint_as_float(w & 0xffff0000u); }
__device__ __forceinline__ unsigned short f2bu(float f)
{
    bf16 h = __float2bfloat16(f);
    return *(unsigned short*)&h;
}

__device__ __forceinline__ int eread(const void* __restrict__ eidx, long long i, int is64)
{
    if (is64) return (int)((const long long*)eidx)[i];
    return ((const int*)eidx)[i];
}

// ---------------- dtype detection ----------------
__global__ void detect_kernel(const unsigned short* __restrict__ xraw,
                              const unsigned int* __restrict__ eraw,
                              int* __restrict__ flags)
{
    __shared__ int s_insane, s_oddnz;
    if (threadIdx.x == 0) { s_insane = 0; s_oddnz = 0; }
    __syncthreads();
    int insane = 0;
    for (int i = threadIdx.x; i < 8192; i += 256) {
        const unsigned int bits = ((unsigned int)xraw[i]) << 16;
        const float v = __uint_as_float(bits);
        const float a = fabsf(v);
        const bool sane = (v == 0.0f) || (a >= 1e-30f && a <= 1e4f);
        if (!sane) insane++;
    }
    int oddnz = 0;
    for (int i = threadIdx.x; i < 512; i += 256) {
        if (eraw[2 * i + 1] != 0u) oddnz++;
    }
    atomicAdd(&s_insane, insane);
    atomicAdd(&s_oddnz, oddnz);
    __syncthreads();
    if (threadIdx.x == 0) {
        flags[0] = (s_insane < 256) ? 1 : 0;
        flags[1] = (s_oddnz == 0) ? 1 : 0;
    }
}

// ---------------- canonicalize all small weights to fp32 ----------------
__global__ void conv_w_kernel(const void* W1, const void* as1, const void* ad1, const void* b1,
                              const void* W2, const void* as2, const void* ad2, const void* b2,
                              float* __restrict__ wc, const int* __restrict__ flags)
{
    const int i = blockIdx.x * blockDim.x + threadIdx.x;
    if (i >= WTOT) return;
    const void* src; int off;
    if (i < OAS1)      { src = W1;  off = i - OW1; }
    else if (i < OAD1) { src = as1; off = i - OAS1; }
    else if (i < OB1)  { src = ad1; off = i - OAD1; }
    else if (i < OW2)  { src = b1;  off = i - OB1; }
    else if (i < OAS2) { src = W2;  off = i - OW2; }
    else if (i < OAD2) { src = as2; off = i - OAS2; }
    else if (i < OB2)  { src = ad2; off = i - OAD2; }
    else               { src = b2;  off = i - OB2; }
    float v;
    if (flags[0]) v = b2f(((const bf16*)src)[off]);
    else          v = ((const float*)src)[off];
    wc[i] = v;
}

// ---------------- W1 -> bf16 transposed+padded [128 cols][512 k] ----------------
__global__ void conv_w1t_kernel(const void* __restrict__ W1, unsigned short* __restrict__ w1t,
                                const int* __restrict__ flags)
{
    const int i = blockIdx.x * blockDim.x + threadIdx.x;   // col*512 + k
    if (i >= HC * KPAD) return;
    const int col = i >> 9;
    const int k   = i & (KPAD - 1);
    float v = 0.f;
    if (k < FIN) {
        if (flags[0]) v = b2f(((const bf16*)W1)[k * HC + col]);
        else          v = ((const float*)W1)[k * HC + col];
    }
    w1t[i] = f2bu(v);
}

// ---------------- CSR build: histogram of dst ----------------
__global__ void hist_kernel(const void* __restrict__ eidx, int* __restrict__ deg,
                            const int* __restrict__ flags)
{
    const int e = blockIdx.x * blockDim.x + threadIdx.x;
    if (e >= ETOT) return;
    int d;
    if (e < EE) d = eread(eidx, (long long)EE + e, flags[1]);
    else        d = e - EE;
    if ((unsigned)d < (unsigned)NN) atomicAdd(&deg[d], 1);
}

// ---------------- scan k1 ----------------
__global__ void scan_k1_kernel(const int* __restrict__ deg, int* __restrict__ bsum)
{
    __shared__ int lds[256];
    const int i = blockIdx.x * 256 + threadIdx.x;
    lds[threadIdx.x] = (i < NN) ? deg[i] : 0;
    __syncthreads();
    for (int s = 128; s > 0; s >>= 1) {
        if (threadIdx.x < s) lds[threadIdx.x] += lds[threadIdx.x + s];
        __syncthreads();
    }
    if (threadIdx.x == 0) bsum[blockIdx.x] = lds[0];
}

// ---------------- scan k2 ----------------
__global__ void scan_k2_kernel(int* __restrict__ bsum)
{
    __shared__ int a[256], b[256], orig[256];
    const int t = threadIdx.x;
    a[t] = bsum[t]; orig[t] = a[t];
    __syncthreads();
    int* cur = a; int* nxt = b;
    for (int off = 1; off < 256; off <<= 1) {
        nxt[t] = cur[t] + ((t >= off) ? cur[t - off] : 0);
        __syncthreads();
        int* tmp = cur; cur = nxt; nxt = tmp;
    }
    bsum[t] = cur[t] - orig[t];
}

// ---------------- scan k3 ----------------
__global__ void scan_k3_kernel(const int* __restrict__ deg, const int* __restrict__ bsum,
                               int* __restrict__ rowptr)
{
    __shared__ int a[256], b[256], own[256];
    const int t = threadIdx.x;
    const int i = blockIdx.x * 256 + t;
    const int v = (i < NN) ? deg[i] : 0;
    a[t] = v; own[t] = v;
    __syncthreads();
    int* cur = a; int* nxt = b;
    for (int off = 1; off < 256; off <<= 1) {
        nxt[t] = cur[t] + ((t >= off) ? cur[t - off] : 0);
        __syncthreads();
        int* tmp = cur; cur = nxt; nxt = tmp;
    }
    if (i < NN) rowptr[i] = bsum[blockIdx.x] + cur[t] - own[t];
}

// ---------------- CSR scatter ----------------
__global__ void scatter_kernel(const void* __restrict__ eidx, int* __restrict__ rowptr,
                               int* __restrict__ esrc_sorted, const int* __restrict__ flags)
{
    const int e = blockIdx.x * blockDim.x + threadIdx.x;
    if (e >= ETOT) return;
    int s, d;
    if (e < EE) {
        s = eread(eidx, e, flags[1]);
        d = eread(eidx, (long long)EE + e, flags[1]);
    } else s = d = e - EE;
    if ((unsigned)s >= (unsigned)NN || (unsigned)d >= (unsigned)NN) return;
    const int pos = atomicAdd(&rowptr[d], 1);
    if ((unsigned)pos < (unsigned)ETOT) esrc_sorted[pos] = s;
}
// After scatter: rowptr[n] == end of segment n; start = (n==0 ? 0 : rowptr[n-1]).

// ---------------- GEMM1 (MFMA bf16) ----------------
__global__ __launch_bounds__(256) void gemm1_mfma_kernel(
    const void* __restrict__ x, const unsigned short* __restrict__ w1t,
    bf16* __restrict__ h1, const int* __restrict__ flags)
{
    __shared__ unsigned short Asl[GR1 * ASTR];
    __shared__ unsigned short Bsl[HC * BSTR];

    const int t    = threadIdx.x;
    const int wv   = t >> 6;
    const int lane = t & 63;
    const int m15  = lane & 15;
    const int quad = lane >> 4;
    const int r0   = blockIdx.x * GR1;
    const int isbf = flags[0];
    const float* xf = (const float*)x;
    const bf16*  xb = (const bf16*)x;

    const int wr  = (wv >> 1) * 32;
    const int wcb = (wv & 1) * 64;

    f32x4 acc[2][4];
#pragma unroll
    for (int i = 0; i < 2; ++i)
#pragma unroll
        for (int j = 0; j < 4; ++j) acc[i][j] = (f32x4){0.f, 0.f, 0.f, 0.f};

    const int arow = t >> 2;
    const int akk  = (t & 3) * 8;
    const int bcol = t & 127;
    const int bks  = (t >> 7) * 16;

    for (int kt = 0; kt < 16; ++kt) {
        const int k0 = kt * GK;
        {
            const int grow = r0 + arow;
            if (!isbf && grow < NN && (k0 + akk + 8) <= FIN) {
                const size_t base = (size_t)grow * FIN + k0 + akk;
                const float4 v0 = *(const float4*)(xf + base);
                const float4 v1 = *(const float4*)(xf + base + 4);
                uint4 pk;
                pk.x = (unsigned)f2bu(v0.x) | ((unsigned)f2bu(v0.y) << 16);
                pk.y = (unsigned)f2bu(v0.z) | ((unsigned)f2bu(v0.w) << 16);
                pk.z = (unsigned)f2bu(v1.x) | ((unsigned)f2bu(v1.y) << 16);
                pk.w = (unsigned)f2bu(v1.z) | ((unsigned)f2bu(v1.w) << 16);
                *(uint4*)&Asl[arow * ASTR + akk] = pk;
            } else {
#pragma unroll
                for (int j = 0; j < 8; ++j) {
                    const int k = k0 + akk + j;
                    float v = 0.f;
                    if (grow < NN && k < FIN)
                        v = isbf ? b2f(xb[(size_t)grow * FIN + k]) : xf[(size_t)grow * FIN + k];
                    Asl[arow * ASTR + akk + j] = f2bu(v);
                }
            }
        }
        {
            const unsigned short* gp = w1t + (size_t)bcol * KPAD + k0 + bks;
            *(uint4*)&Bsl[bcol * BSTR + bks]     = *(const uint4*)gp;
            *(uint4*)&Bsl[bcol * BSTR + bks + 8] = *(const uint4*)(gp + 8);
        }
        __syncthreads();

        const int ak = quad * 8;
        const short8 a0 = *(const short8*)&Asl[(wr + m15) * ASTR + ak];
        const short8 a1 = *(const short8*)&Asl[(wr + 16 + m15) * ASTR + ak];
#pragma unroll
        for (int ct = 0; ct < 4; ++ct) {
            const short8 b = *(const short8*)&Bsl[(wcb + ct * 16 + m15) * BSTR + ak];
            acc[0][ct] = __builtin_amdgcn_mfma_f32_16x16x32_bf16(a0, b, acc[0][ct], 0, 0, 0);
            acc[1][ct] = __builtin_amdgcn_mfma_f32_16x16x32_bf16(a1, b, acc[1][ct], 0, 0, 0);
        }
        __syncthreads();
    }

#pragma unroll
    for (int rt = 0; rt < 2; ++rt) {
#pragma unroll
        for (int reg = 0; reg < 4; ++reg) {
            const int row = r0 + wr + rt * 16 + quad * 4 + reg;
            if (row < NN) {
                bf16* hp = h1 + (size_t)row * HC;
#pragma unroll
                for (int ct = 0; ct < 4; ++ct)
                    hp[wcb + ct * 16 + m15] = __float2bfloat16(acc[rt][ct][reg]);
            }
        }
    }
}

// ---------------- per-node attention logits, layer 1 ----------------
__global__ void att1_kernel(const bf16* __restrict__ h1, const float* __restrict__ wc,
                            float* __restrict__ a_src, float* __restrict__ a_dst)
{
    const int idx = blockIdx.x * blockDim.x + threadIdx.x;   // n*8 + h
    if (idx >= NN * NH) return;
    const int h = idx & 7;
    const unsigned int* hp = (const unsigned int*)(h1 + (size_t)(idx >> 3) * HC + h * CH);
    float s = 0.f, d = 0.f;
#pragma unroll
    for (int u = 0; u < 8; ++u) {
        const unsigned int w = hp[u];
        s += blo(w) * wc[OAS1 + h * CH + 2 * u] + bhi(w) * wc[OAS1 + h * CH + 2 * u + 1];
        d += blo(w) * wc[OAD1 + h * CH + 2 * u] + bhi(w) * wc[OAD1 + h * CH + 2 * u + 1];
    }
    a_src[idx] = s;
    a_dst[idx] = d;
}

// ---------------- layer-1 fused gather, 4-way unrolled for MLP ----------------
__global__ __launch_bounds__(256) void gather1_kernel(
    const int* __restrict__ rowptr, const int* __restrict__ esrc_sorted,
    const float* __restrict__ a_src, const float* __restrict__ a_dst,
    const bf16* __restrict__ h1, float* __restrict__ out1)
{
    const int node = blockIdx.x * 4 + (threadIdx.x >> 6);
    if (node >= NN) return;
    const int lane = threadIdx.x & 63;
    const int h = lane >> 3;
    const float ad = a_dst[node * NH + h];
    const int start = (node == 0) ? 0 : rowptr[node - 1];
    const int end   = rowptr[node];
    float acc0 = 0.f, acc1 = 0.f, den = 0.f;
    int i = start;
    for (; i + 4 <= end; i += 4) {
        const int s0 = esrc_sorted[i + 0];
        const int s1 = esrc_sorted[i + 1];
        const int s2 = esrc_sorted[i + 2];
        const int s3 = esrc_sorted[i + 3];
        const float e0 = a_src[s0 * NH + h];
        const float e1 = a_src[s1 * NH + h];
        const float e2 = a_src[s2 * NH + h];
        const float e3 = a_src[s3 * NH + h];
        const unsigned w0 = *(const unsigned*)(h1 + (size_t)s0 * HC + 2 * lane);
        const unsigned w1 = *(const unsigned*)(h1 + (size_t)s1 * HC + 2 * lane);
        const unsigned w2 = *(const unsigned*)(h1 + (size_t)s2 * HC + 2 * lane);
        const unsigned w3 = *(const unsigned*)(h1 + (size_t)s3 * HC + 2 * lane);
        const float n0 = elog(e0 + ad);
        const float n1 = elog(e1 + ad);
        const float n2 = elog(e2 + ad);
        const float n3 = elog(e3 + ad);
        acc0 += n0 * blo(w0) + n1 * blo(w1) + n2 * blo(w2) + n3 * blo(w3);
        acc1 += n0 * bhi(w0) + n1 * bhi(w1) + n2 * bhi(w2) + n3 * bhi(w3);
        den  += n0 + n1 + n2 + n3;
    }
    for (; i < end; ++i) {
        const int s = esrc_sorted[i];
        const float num = elog(a_src[s * NH + h] + ad);
        const unsigned w = *(const unsigned*)(h1 + (size_t)s * HC + 2 * lane);
        acc0 += num * blo(w);
        acc1 += num * bhi(w);
        den  += num;
    }
    const float inv = 1.f / (den + 1e-16f);
    float* op = out1 + (size_t)node * HC + 2 * lane;
    op[0] = acc0 * inv;
    op[1] = acc1 * inv;
}

// ---------------- GEMM2 with fused bias+relu ----------------
__global__ __launch_bounds__(256) void gemm2_kernel(
    const float* __restrict__ out1, const float* __restrict__ wc, float* __restrict__ h2)
{
    __shared__ float W2s[HC * NC];
    __shared__ float B1s[HC];
    for (int i = threadIdx.x; i < HC * NC; i += 256) W2s[i] = wc[OW2 + i];
    if (threadIdx.x < HC) B1s[threadIdx.x] = wc[OB1 + threadIdx.x];
    __syncthreads();
    const int nl = threadIdx.x >> 3;
    const int c  = threadIdx.x & 7;
    const int node = blockIdx.x * 32 + nl;
    if (c >= NC || node >= NN) return;
    const float* hp = out1 + (size_t)node * HC;
    float acc = 0.f;
#pragma unroll
    for (int k4 = 0; k4 < 32; ++k4) {
        const float4 hv = *(const float4*)&hp[4 * k4];
        acc += fmaxf(hv.x + B1s[4 * k4 + 0], 0.f) * W2s[(4 * k4 + 0) * NC + c];
        acc += fmaxf(hv.y + B1s[4 * k4 + 1], 0.f) * W2s[(4 * k4 + 1) * NC + c];
        acc += fmaxf(hv.z + B1s[4 * k4 + 2], 0.f) * W2s[(4 * k4 + 2) * NC + c];
        acc += fmaxf(hv.w + B1s[4 * k4 + 3], 0.f) * W2s[(4 * k4 + 3) * NC + c];
    }
    h2[node * NC + c] = acc;
}

// ---------------- per-node attention logits, layer 2 ----------------
__global__ void att2_kernel(const float* __restrict__ h2, const float* __restrict__ wc,
                            float* __restrict__ a_src, float* __restrict__ a_dst)
{
    const int n = blockIdx.x * blockDim.x + threadIdx.x;
    if (n >= NN) return;
    float s = 0.f, d = 0.f;
#pragma unroll
    for (int c = 0; c < NC; ++c) {
        const float hv = h2[n * NC + c];
        s += hv * wc[OAS2 + c];
        d += hv * wc[OAD2 + c];
    }
    a_src[n] = s;
    a_dst[n] = d;
}

// ---------------- layer-2 fused gather, 4-way unrolled ----------------
__global__ __launch_bounds__(256) void gather2_kernel(
    const int* __restrict__ rowptr, const int* __restrict__ esrc_sorted,
    const float* __restrict__ a_src, const float* __restrict__ a_dst,
    const float* __restrict__ h2, const float* __restrict__ wc,
    void* __restrict__ out, const int* __restrict__ flags)
{
    const int node = blockIdx.x * 32 + (threadIdx.x >> 3);
    if (node >= NN) return;
    const int c = threadIdx.x & 7;
    const float ad = a_dst[node];
    const int start = (node == 0) ? 0 : rowptr[node - 1];
    const int end   = rowptr[node];
    const int cc = (c < NC) ? c : 0;
    float acc = 0.f, den = 0.f;
    int i = start;
    for (; i + 4 <= end; i += 4) {
        const int s0 = esrc_sorted[i + 0];
        const int s1 = esrc_sorted[i + 1];
        const int s2 = esrc_sorted[i + 2];
        const int s3 = esrc_sorted[i + 3];
        const float e0 = a_src[s0];
        const float e1 = a_src[s1];
        const float e2 = a_src[s2];
        const float e3 = a_src[s3];
        const float v0 = h2[s0 * NC + cc];
        const float v1 = h2[s1 * NC + cc];
        const float v2 = h2[s2 * NC + cc];
        const float v3 = h2[s3 * NC + cc];
        const float n0 = elog(e0 + ad);
        const float n1 = elog(e1 + ad);
        const float n2 = elog(e2 + ad);
        const float n3 = elog(e3 + ad);
        acc += n0 * v0 + n1 * v1 + n2 * v2 + n3 * v3;
        den += n0 + n1 + n2 + n3;
    }
    for (; i < end; ++i) {
        const int s = esrc_sorted[i];
        const float num = elog(a_src[s] + ad);
        den += num;
        acc += num * h2[s * NC + cc];
    }
    if (c >= NC) return;
    const float v = acc / (den + 1e-16f) + wc[OB2 + c];
    if (flags[0]) ((bf16*)out)[node * NC + c] = __float2bfloat16(v);
    else          ((float*)out)[node * NC + c] = v;
}

extern "C" void kernel_launch(void* const* d_in, const int* in_sizes, int n_in,
                              void* d_out, int out_size, void* d_ws, size_t ws_size,
                              hipStream_t stream)
{
    const void* x        = d_in[0];
    const void* eidx     = d_in[1];
    const void* W1       = d_in[2];
    const void* att_src1 = d_in[3];
    const void* att_dst1 = d_in[4];
    const void* b1       = d_in[5];
    const void* W2       = d_in[6];
    const void* att_src2 = d_in[7];
    const void* att_dst2 = d_in[8];
    const void* b2       = d_in[9];

    float* ws = (float*)d_ws;
    size_t o = 0;
    int*   flags  = (int*)(ws + o);            o += 16;
    float* wc     = ws + o;                    o += 65312;
    unsigned short* w1t = (unsigned short*)(ws + o); o += (HC * KPAD) / 2;
    int*   deg    = (int*)(ws + o);            o += 50000;
    int*   rowptr = (int*)(ws + o);            o += 50016;
    int*   bsum   = (int*)(ws + o);            o += 256;
    int*   esrt   = (int*)(ws + o);            o += 850000;
    bf16*  h1     = (bf16*)(ws + o);           o += (size_t)NN * HC / 2;
    float* a_src1 = ws + o;                    o += (size_t)NN * NH;
    float* a_dst1 = ws + o;                    o += (size_t)NN * NH;
    float* out1   = ws + o;                    o += (size_t)NN * HC;
    float* h2     = ws + o;                    o += (size_t)NN * NC;
    float* a_src2 = ws + o;                    o += NN;
    float* a_dst2 = ws + o;                    o += NN;

    detect_kernel<<<1, 256, 0, stream>>>((const unsigned short*)x, (const unsigned int*)eidx, flags);
    conv_w_kernel<<<(WTOT + 255) / 256, 256, 0, stream>>>(W1, att_src1, att_dst1, b1,
                                                          W2, att_src2, att_dst2, b2, wc, flags);
    conv_w1t_kernel<<<(HC * KPAD + 255) / 256, 256, 0, stream>>>(W1, w1t, flags);
    hipMemsetAsync(deg, 0, (size_t)NN * sizeof(int), stream);
    hist_kernel<<<(ETOT + 255) / 256, 256, 0, stream>>>(eidx, deg, flags);
    scan_k1_kernel<<<(NN + 255) / 256, 256, 0, stream>>>(deg, bsum);
    scan_k2_kernel<<<1, 256, 0, stream>>>(bsum);
    scan_k3_kernel<<<(NN + 255) / 256, 256, 0, stream>>>(deg, bsum, rowptr);
    scatter_kernel<<<(ETOT + 255) / 256, 256, 0, stream>>>(eidx, rowptr, esrt, flags);

    gemm1_mfma_kernel<<<(NN + GR1 - 1) / GR1, 256, 0, stream>>>(x, w1t, h1, flags);
    att1_kernel<<<(NN * NH + 255) / 256, 256, 0, stream>>>(h1, wc, a_src1, a_dst1);
    gather1_kernel<<<(NN + 3) / 4, 256, 0, stream>>>(rowptr, esrt, a_src1, a_dst1, h1, out1);
    gemm2_kernel<<<(NN + 31) / 32, 256, 0, stream>>>(out1, wc, h2);
    att2_kernel<<<(NN + 255) / 256, 256, 0, stream>>>(h2, wc, a_src2, a_dst2);
    gather2_kernel<<<(NN + 31) / 32, 256, 0, stream>>>(rowptr, esrt, a_src2, a_dst2, h2, wc, d_out, flags);
}

// Round 9
// 339.789 us; speedup vs baseline: 4.1657x; 1.1261x over previous
//
#include <hip/hip_runtime.h>
#include <hip/hip_bf16.h>

#define NN 50000
#define EE 800000
#define ETOT 850000   // EE + NN self-loops
#define FIN 500
#define HC 128        // 8 heads * 16 ch
#define NH 8
#define CH 16
#define NC 7

// canonical fp32 weight-buffer offsets
#define OW1  0
#define OAS1 64000
#define OAD1 64128
#define OB1  64256
#define OW2  64384
#define OAS2 65280
#define OAD2 65287
#define OB2  65294
#define WTOT 65301

// MFMA gemm1 tiling
#define GR1  64
#define GK   32
#define KPAD 512
#define ASTR 40
#define BSTR 40

typedef __hip_bfloat16 bf16;
typedef __attribute__((ext_vector_type(8))) short short8;
typedef __attribute__((ext_vector_type(4))) float f32x4;

__device__ __forceinline__ float b2f(const bf16 v) { return __bfloat162float(v); }
__device__ __forceinline__ float lrelu(float v) { return fmaxf(v, 0.2f * v); }
__device__ __forceinline__ float elog(float v) { return __expf(fminf(lrelu(v), 30.f)); }
__device__ __forceinline__ float blo(unsigned w) { return __uint_as_float(w << 16); }
__device__ __forceinline__ float bhi(unsigned w) { return __uint_as_float(w & 0xffff0000u); }
__device__ __forceinline__ unsigned short f2bu(float f)
{
    bf16 h = __float2bfloat16(f);
    return *(unsigned short*)&h;
}

__device__ __forceinline__ int eread(const void* __restrict__ eidx, long long i, int is64)
{
    if (is64) return (int)((const long long*)eidx)[i];
    return ((const int*)eidx)[i];
}

// ---------------- dtype detection + rowptr sentinel ----------------
__global__ void detect_kernel(const unsigned short* __restrict__ xraw,
                              const unsigned int* __restrict__ eraw,
                              int* __restrict__ flags, int* __restrict__ rowptr)
{
    __shared__ int s_insane, s_oddnz;
    if (threadIdx.x == 0) { s_insane = 0; s_oddnz = 0; }
    __syncthreads();
    int insane = 0;
    for (int i = threadIdx.x; i < 8192; i += 256) {
        const unsigned int bits = ((unsigned int)xraw[i]) << 16;
        const float v = __uint_as_float(bits);
        const float a = fabsf(v);
        const bool sane = (v == 0.0f) || (a >= 1e-30f && a <= 1e4f);
        if (!sane) insane++;
    }
    int oddnz = 0;
    for (int i = threadIdx.x; i < 512; i += 256) {
        if (eraw[2 * i + 1] != 0u) oddnz++;
    }
    atomicAdd(&s_insane, insane);
    atomicAdd(&s_oddnz, oddnz);
    __syncthreads();
    if (threadIdx.x == 0) {
        flags[0] = (s_insane < 256) ? 1 : 0;
        flags[1] = (s_oddnz == 0) ? 1 : 0;
        rowptr[NN] = ETOT;   // sentinel: rowptr holds immutable starts + end
    }
}

// ---------------- canonicalize all small weights to fp32 ----------------
__global__ void conv_w_kernel(const void* W1, const void* as1, const void* ad1, const void* b1,
                              const void* W2, const void* as2, const void* ad2, const void* b2,
                              float* __restrict__ wc, const int* __restrict__ flags)
{
    const int i = blockIdx.x * blockDim.x + threadIdx.x;
    if (i >= WTOT) return;
    const void* src; int off;
    if (i < OAS1)      { src = W1;  off = i - OW1; }
    else if (i < OAD1) { src = as1; off = i - OAS1; }
    else if (i < OB1)  { src = ad1; off = i - OAD1; }
    else if (i < OW2)  { src = b1;  off = i - OB1; }
    else if (i < OAS2) { src = W2;  off = i - OW2; }
    else if (i < OAD2) { src = as2; off = i - OAS2; }
    else if (i < OB2)  { src = ad2; off = i - OAD2; }
    else               { src = b2;  off = i - OB2; }
    float v;
    if (flags[0]) v = b2f(((const bf16*)src)[off]);
    else          v = ((const float*)src)[off];
    wc[i] = v;
}

// ---------------- W1 -> bf16 transposed+padded [128 cols][512 k] ----------------
__global__ void conv_w1t_kernel(const void* __restrict__ W1, unsigned short* __restrict__ w1t,
                                const int* __restrict__ flags)
{
    const int i = blockIdx.x * blockDim.x + threadIdx.x;
    if (i >= HC * KPAD) return;
    const int col = i >> 9;
    const int k   = i & (KPAD - 1);
    float v = 0.f;
    if (k < FIN) {
        if (flags[0]) v = b2f(((const bf16*)W1)[k * HC + col]);
        else          v = ((const float*)W1)[k * HC + col];
    }
    w1t[i] = f2bu(v);
}

// ---------------- CSR build: histogram of dst + per-edge rank ----------------
__global__ void hist_kernel(const void* __restrict__ eidx, int* __restrict__ deg,
                            int* __restrict__ rank, const int* __restrict__ flags)
{
    const int e = blockIdx.x * blockDim.x + threadIdx.x;
    if (e >= ETOT) return;
    int d;
    if (e < EE) d = eread(eidx, (long long)EE + e, flags[1]);
    else        d = e - EE;
    int r = -1;
    if ((unsigned)d < (unsigned)NN) r = atomicAdd(&deg[d], 1);
    rank[e] = r;
}

// ---------------- scan k1 ----------------
__global__ void scan_k1_kernel(const int* __restrict__ deg, int* __restrict__ bsum)
{
    __shared__ int lds[256];
    const int i = blockIdx.x * 256 + threadIdx.x;
    lds[threadIdx.x] = (i < NN) ? deg[i] : 0;
    __syncthreads();
    for (int s = 128; s > 0; s >>= 1) {
        if (threadIdx.x < s) lds[threadIdx.x] += lds[threadIdx.x + s];
        __syncthreads();
    }
    if (threadIdx.x == 0) bsum[blockIdx.x] = lds[0];
}

// ---------------- scan k2 ----------------
__global__ void scan_k2_kernel(int* __restrict__ bsum)
{
    __shared__ int a[256], b[256], orig[256];
    const int t = threadIdx.x;
    a[t] = bsum[t]; orig[t] = a[t];
    __syncthreads();
    int* cur = a; int* nxt = b;
    for (int off = 1; off < 256; off <<= 1) {
        nxt[t] = cur[t] + ((t >= off) ? cur[t - off] : 0);
        __syncthreads();
        int* tmp = cur; cur = nxt; nxt = tmp;
    }
    bsum[t] = cur[t] - orig[t];
}

// ---------------- scan k3: rowptr[i] = exclusive start of node i ----------------
__global__ void scan_k3_kernel(const int* __restrict__ deg, const int* __restrict__ bsum,
                               int* __restrict__ rowptr)
{
    __shared__ int a[256], b[256], own[256];
    const int t = threadIdx.x;
    const int i = blockIdx.x * 256 + t;
    const int v = (i < NN) ? deg[i] : 0;
    a[t] = v; own[t] = v;
    __syncthreads();
    int* cur = a; int* nxt = b;
    for (int off = 1; off < 256; off <<= 1) {
        nxt[t] = cur[t] + ((t >= off) ? cur[t - off] : 0);
        __syncthreads();
        int* tmp = cur; cur = nxt; nxt = tmp;
    }
    if (i < NN) rowptr[i] = bsum[blockIdx.x] + cur[t] - own[t];
}

// ---------------- CSR scatter, atomic-free: pos = rowptr[d] + rank[e] ----------------
__global__ void scatter_kernel(const void* __restrict__ eidx, const int* __restrict__ rowptr,
                               const int* __restrict__ rank, int* __restrict__ esrc_sorted,
                               const int* __restrict__ flags)
{
    const int e = blockIdx.x * blockDim.x + threadIdx.x;
    if (e >= ETOT) return;
    int s, d;
    if (e < EE) {
        s = eread(eidx, e, flags[1]);
        d = eread(eidx, (long long)EE + e, flags[1]);
    } else s = d = e - EE;
    if ((unsigned)s >= (unsigned)NN || (unsigned)d >= (unsigned)NN) return;
    const int r = rank[e];
    if (r < 0) return;
    const int pos = rowptr[d] + r;
    if ((unsigned)pos < (unsigned)ETOT) esrc_sorted[pos] = s;
}

// ---------------- GEMM1 (MFMA bf16) ----------------
__global__ __launch_bounds__(256) void gemm1_mfma_kernel(
    const void* __restrict__ x, const unsigned short* __restrict__ w1t,
    bf16* __restrict__ h1, const int* __restrict__ flags)
{
    __shared__ unsigned short Asl[GR1 * ASTR];
    __shared__ unsigned short Bsl[HC * BSTR];

    const int t    = threadIdx.x;
    const int wv   = t >> 6;
    const int lane = t & 63;
    const int m15  = lane & 15;
    const int quad = lane >> 4;
    const int r0   = blockIdx.x * GR1;
    const int isbf = flags[0];
    const float* xf = (const float*)x;
    const bf16*  xb = (const bf16*)x;

    const int wr  = (wv >> 1) * 32;
    const int wcb = (wv & 1) * 64;

    f32x4 acc[2][4];
#pragma unroll
    for (int i = 0; i < 2; ++i)
#pragma unroll
        for (int j = 0; j < 4; ++j) acc[i][j] = (f32x4){0.f, 0.f, 0.f, 0.f};

    const int arow = t >> 2;
    const int akk  = (t & 3) * 8;
    const int bcol = t & 127;
    const int bks  = (t >> 7) * 16;

    for (int kt = 0; kt < 16; ++kt) {
        const int k0 = kt * GK;
        {
            const int grow = r0 + arow;
            if (!isbf && grow < NN && (k0 + akk + 8) <= FIN) {
                const size_t base = (size_t)grow * FIN + k0 + akk;
                const float4 v0 = *(const float4*)(xf + base);
                const float4 v1 = *(const float4*)(xf + base + 4);
                uint4 pk;
                pk.x = (unsigned)f2bu(v0.x) | ((unsigned)f2bu(v0.y) << 16);
                pk.y = (unsigned)f2bu(v0.z) | ((unsigned)f2bu(v0.w) << 16);
                pk.z = (unsigned)f2bu(v1.x) | ((unsigned)f2bu(v1.y) << 16);
                pk.w = (unsigned)f2bu(v1.z) | ((unsigned)f2bu(v1.w) << 16);
                *(uint4*)&Asl[arow * ASTR + akk] = pk;
            } else {
#pragma unroll
                for (int j = 0; j < 8; ++j) {
                    const int k = k0 + akk + j;
                    float v = 0.f;
                    if (grow < NN && k < FIN)
                        v = isbf ? b2f(xb[(size_t)grow * FIN + k]) : xf[(size_t)grow * FIN + k];
                    Asl[arow * ASTR + akk + j] = f2bu(v);
                }
            }
        }
        {
            const unsigned short* gp = w1t + (size_t)bcol * KPAD + k0 + bks;
            *(uint4*)&Bsl[bcol * BSTR + bks]     = *(const uint4*)gp;
            *(uint4*)&Bsl[bcol * BSTR + bks + 8] = *(const uint4*)(gp + 8);
        }
        __syncthreads();

        const int ak = quad * 8;
        const short8 a0 = *(const short8*)&Asl[(wr + m15) * ASTR + ak];
        const short8 a1 = *(const short8*)&Asl[(wr + 16 + m15) * ASTR + ak];
#pragma unroll
        for (int ct = 0; ct < 4; ++ct) {
            const short8 b = *(const short8*)&Bsl[(wcb + ct * 16 + m15) * BSTR + ak];
            acc[0][ct] = __builtin_amdgcn_mfma_f32_16x16x32_bf16(a0, b, acc[0][ct], 0, 0, 0);
            acc[1][ct] = __builtin_amdgcn_mfma_f32_16x16x32_bf16(a1, b, acc[1][ct], 0, 0, 0);
        }
        __syncthreads();
    }

#pragma unroll
    for (int rt = 0; rt < 2; ++rt) {
#pragma unroll
        for (int reg = 0; reg < 4; ++reg) {
            const int row = r0 + wr + rt * 16 + quad * 4 + reg;
            if (row < NN) {
                bf16* hp = h1 + (size_t)row * HC;
#pragma unroll
                for (int ct = 0; ct < 4; ++ct)
                    hp[wcb + ct * 16 + m15] = __float2bfloat16(acc[rt][ct][reg]);
            }
        }
    }
}

// ---------------- per-node attention logits, layer 1 ----------------
__global__ void att1_kernel(const bf16* __restrict__ h1, const float* __restrict__ wc,
                            float* __restrict__ a_src, float* __restrict__ a_dst)
{
    const int idx = blockIdx.x * blockDim.x + threadIdx.x;
    if (idx >= NN * NH) return;
    const int h = idx & 7;
    const unsigned int* hp = (const unsigned int*)(h1 + (size_t)(idx >> 3) * HC + h * CH);
    float s = 0.f, d = 0.f;
#pragma unroll
    for (int u = 0; u < 8; ++u) {
        const unsigned int w = hp[u];
        s += blo(w) * wc[OAS1 + h * CH + 2 * u] + bhi(w) * wc[OAS1 + h * CH + 2 * u + 1];
        d += blo(w) * wc[OAD1 + h * CH + 2 * u] + bhi(w) * wc[OAD1 + h * CH + 2 * u + 1];
    }
    a_src[idx] = s;
    a_dst[idx] = d;
}

// ---------------- layer-1 fused gather, 8-way unrolled ----------------
__global__ __launch_bounds__(256) void gather1_kernel(
    const int* __restrict__ rowptr, const int* __restrict__ esrc_sorted,
    const float* __restrict__ a_src, const float* __restrict__ a_dst,
    const bf16* __restrict__ h1, float* __restrict__ out1)
{
    const int node = blockIdx.x * 4 + (threadIdx.x >> 6);
    if (node >= NN) return;
    const int lane = threadIdx.x & 63;
    const int h = lane >> 3;
    const float ad = a_dst[node * NH + h];
    const int start = rowptr[node];
    const int end   = rowptr[node + 1];
    float acc0 = 0.f, acc1 = 0.f, den = 0.f;
    int i = start;
    for (; i + 8 <= end; i += 8) {
        int   sv[8];
        float ev[8];
        unsigned wv[8];
#pragma unroll
        for (int j = 0; j < 8; ++j) sv[j] = esrc_sorted[i + j];
#pragma unroll
        for (int j = 0; j < 8; ++j) ev[j] = a_src[sv[j] * NH + h];
#pragma unroll
        for (int j = 0; j < 8; ++j) wv[j] = *(const unsigned*)(h1 + (size_t)sv[j] * HC + 2 * lane);
#pragma unroll
        for (int j = 0; j < 8; ++j) {
            const float n = elog(ev[j] + ad);
            acc0 += n * blo(wv[j]);
            acc1 += n * bhi(wv[j]);
            den  += n;
        }
    }
    for (; i < end; ++i) {
        const int s = esrc_sorted[i];
        const float num = elog(a_src[s * NH + h] + ad);
        const unsigned w = *(const unsigned*)(h1 + (size_t)s * HC + 2 * lane);
        acc0 += num * blo(w);
        acc1 += num * bhi(w);
        den  += num;
    }
    const float inv = 1.f / (den + 1e-16f);
    float* op = out1 + (size_t)node * HC + 2 * lane;
    op[0] = acc0 * inv;
    op[1] = acc1 * inv;
}

// ---------------- GEMM2 + fused bias/relu + fused att2 logits ----------------
__global__ __launch_bounds__(256) void gemm2_kernel(
    const float* __restrict__ out1, const float* __restrict__ wc, float* __restrict__ h2,
    float* __restrict__ a_src2, float* __restrict__ a_dst2)
{
    __shared__ float W2s[HC * NC];
    __shared__ float B1s[HC];
    for (int i = threadIdx.x; i < HC * NC; i += 256) W2s[i] = wc[OW2 + i];
    if (threadIdx.x < HC) B1s[threadIdx.x] = wc[OB1 + threadIdx.x];
    __syncthreads();
    const int nl = threadIdx.x >> 3;
    const int c  = threadIdx.x & 7;
    const int node = blockIdx.x * 32 + nl;
    const bool valid = (node < NN) && (c < NC);
    float acc = 0.f;
    if (valid) {
        const float* hp = out1 + (size_t)node * HC;
#pragma unroll
        for (int k4 = 0; k4 < 32; ++k4) {
            const float4 hv = *(const float4*)&hp[4 * k4];
            acc += fmaxf(hv.x + B1s[4 * k4 + 0], 0.f) * W2s[(4 * k4 + 0) * NC + c];
            acc += fmaxf(hv.y + B1s[4 * k4 + 1], 0.f) * W2s[(4 * k4 + 1) * NC + c];
            acc += fmaxf(hv.z + B1s[4 * k4 + 2], 0.f) * W2s[(4 * k4 + 2) * NC + c];
            acc += fmaxf(hv.w + B1s[4 * k4 + 3], 0.f) * W2s[(4 * k4 + 3) * NC + c];
        }
        h2[node * NC + c] = acc;
    }
    // fused att2: reduce acc*as2[c] / acc*ad2[c] over the 8 lanes of this node
    float ps = valid ? acc * wc[OAS2 + c] : 0.f;
    float pd = valid ? acc * wc[OAD2 + c] : 0.f;
#pragma unroll
    for (int m = 1; m < 8; m <<= 1) {
        ps += __shfl_xor(ps, m, 8);
        pd += __shfl_xor(pd, m, 8);
    }
    if (node < NN && c == 0) {
        a_src2[node] = ps;
        a_dst2[node] = pd;
    }
}

// ---------------- layer-2 fused gather ----------------
__global__ __launch_bounds__(256) void gather2_kernel(
    const int* __restrict__ rowptr, const int* __restrict__ esrc_sorted,
    const float* __restrict__ a_src, const float* __restrict__ a_dst,
    const float* __restrict__ h2, const float* __restrict__ wc,
    void* __restrict__ out, const int* __restrict__ flags)
{
    const int node = blockIdx.x * 32 + (threadIdx.x >> 3);
    if (node >= NN) return;
    const int c = threadIdx.x & 7;
    const float ad = a_dst[node];
    const int start = rowptr[node];
    const int end   = rowptr[node + 1];
    const int cc = (c < NC) ? c : 0;
    float acc = 0.f, den = 0.f;
    int i = start;
    for (; i + 4 <= end; i += 4) {
        const int s0 = esrc_sorted[i + 0];
        const int s1 = esrc_sorted[i + 1];
        const int s2 = esrc_sorted[i + 2];
        const int s3 = esrc_sorted[i + 3];
        const float e0 = a_src[s0];
        const float e1 = a_src[s1];
        const float e2 = a_src[s2];
        const float e3 = a_src[s3];
        const float v0 = h2[s0 * NC + cc];
        const float v1 = h2[s1 * NC + cc];
        const float v2 = h2[s2 * NC + cc];
        const float v3 = h2[s3 * NC + cc];
        const float n0 = elog(e0 + ad);
        const float n1 = elog(e1 + ad);
        const float n2 = elog(e2 + ad);
        const float n3 = elog(e3 + ad);
        acc += n0 * v0 + n1 * v1 + n2 * v2 + n3 * v3;
        den += n0 + n1 + n2 + n3;
    }
    for (; i < end; ++i) {
        const int s = esrc_sorted[i];
        const float num = elog(a_src[s] + ad);
        den += num;
        acc += num * h2[s * NC + cc];
    }
    if (c >= NC) return;
    const float v = acc / (den + 1e-16f) + wc[OB2 + c];
    if (flags[0]) ((bf16*)out)[node * NC + c] = __float2bfloat16(v);
    else          ((float*)out)[node * NC + c] = v;
}

extern "C" void kernel_launch(void* const* d_in, const int* in_sizes, int n_in,
                              void* d_out, int out_size, void* d_ws, size_t ws_size,
                              hipStream_t stream)
{
    const void* x        = d_in[0];
    const void* eidx     = d_in[1];
    const void* W1       = d_in[2];
    const void* att_src1 = d_in[3];
    const void* att_dst1 = d_in[4];
    const void* b1       = d_in[5];
    const void* W2       = d_in[6];
    const void* att_src2 = d_in[7];
    const void* att_dst2 = d_in[8];
    const void* b2       = d_in[9];

    float* ws = (float*)d_ws;
    size_t o = 0;
    int*   flags  = (int*)(ws + o);            o += 16;
    float* wc     = ws + o;                    o += 65312;
    unsigned short* w1t = (unsigned short*)(ws + o); o += (HC * KPAD) / 2;
    int*   deg    = (int*)(ws + o);            o += 50000;
    int*   rowptr = (int*)(ws + o);            o += 50016;
    int*   bsum   = (int*)(ws + o);            o += 256;
    int*   esrt   = (int*)(ws + o);            o += 850000;
    int*   rank   = (int*)(ws + o);            o += 850000;
    bf16*  h1     = (bf16*)(ws + o);           o += (size_t)NN * HC / 2;
    float* a_src1 = ws + o;                    o += (size_t)NN * NH;
    float* a_dst1 = ws + o;                    o += (size_t)NN * NH;
    float* out1   = ws + o;                    o += (size_t)NN * HC;
    float* h2     = ws + o;                    o += (size_t)NN * NC;
    float* a_src2 = ws + o;                    o += NN;
    float* a_dst2 = ws + o;                    o += NN;
    // ~51.3 MB; d_ws is ~400 MB (observed fillBufferAligned poison size)

    detect_kernel<<<1, 256, 0, stream>>>((const unsigned short*)x, (const unsigned int*)eidx,
                                         flags, rowptr);
    conv_w_kernel<<<(WTOT + 255) / 256, 256, 0, stream>>>(W1, att_src1, att_dst1, b1,
                                                          W2, att_src2, att_dst2, b2, wc, flags);
    conv_w1t_kernel<<<(HC * KPAD + 255) / 256, 256, 0, stream>>>(W1, w1t, flags);
    hipMemsetAsync(deg, 0, (size_t)NN * sizeof(int), stream);
    hist_kernel<<<(ETOT + 255) / 256, 256, 0, stream>>>(eidx, deg, rank, flags);
    scan_k1_kernel<<<(NN + 255) / 256, 256, 0, stream>>>(deg, bsum);
    scan_k2_kernel<<<1, 256, 0, stream>>>(bsum);
    scan_k3_kernel<<<(NN + 255) / 256, 256, 0, stream>>>(deg, bsum, rowptr);
    scatter_kernel<<<(ETOT + 255) / 256, 256, 0, stream>>>(eidx, rowptr, rank, esrt, flags);

    gemm1_mfma_kernel<<<(NN + GR1 - 1) / GR1, 256, 0, stream>>>(x, w1t, h1, flags);
    att1_kernel<<<(NN * NH + 255) / 256, 256, 0, stream>>>(h1, wc, a_src1, a_dst1);
    gather1_kernel<<<(NN + 3) / 4, 256, 0, stream>>>(rowptr, esrt, a_src1, a_dst1, h1, out1);
    gemm2_kernel<<<(NN + 31) / 32, 256, 0, stream>>>(out1, wc, h2, a_src2, a_dst2);
    gather2_kernel<<<(NN + 31) / 32, 256, 0, stream>>>(rowptr, esrt, a_src2, a_dst2, h2, wc, d_out, flags);
}